// Round 4
// baseline (7661.078 us; speedup 1.0000x reference)
//
#include <hip/hip_runtime.h>
#include <hip/hip_bf16.h>

// trajectory2seq: 2-layer Elman RNN encoder (SEQ=256) + greedy decoder (32 steps)
//  - encoder ih-parts hoisted into two big fp32 GEMMs (k_gemm)
//  - persistent scan kernels for the hh-recurrence (weights in VGPRs, flag barriers)
//  - decoder: one persistent kernel; cell in fp32 (LDS weights), logits via bf16 MFMA
//    + exact-fp32 argmax refinement (margin 0.05)
// R2: ALL intra-kernel cross-wg traffic via device-scope RELAXED atomics.
// R3: phase C Wfcb strip double-buffered through LDS via global_load_lds_dwordx4,
// counted vmcnt(8) pipeline (kept).
// R4: HIERARCHICAL barriers. The flat barrier had 256wgs x 64lanes x 4 flag-lines
// polling = ~65K scattered 4B LLC txns per ~0.4us round -> fabric saturation
// (~25us per full barrier; matches the unexplained ~90us/step and k_scan's 6us/step).
// Now: per-wg arrival flags (parallel), group-master polls arrivals, publishes ONE
// release line; everyone else polls that line with ONE lane. ~130x less poll traffic.
// Also: flag pad 64->128B (no LLC line sharing), pmaxp transposed to b-major so
// phase E reads 16 contiguous lines instead of 250 scattered ones.

typedef float v4f __attribute__((ext_vector_type(4)));
typedef short short8 __attribute__((ext_vector_type(8)));
typedef unsigned long long u64;

#define HID 512
#define NBAT 64
#define SEQL 256
#define NV 32000
#define TDEC 32
#define BH (64 * 512)
#define FPAD 32  // flags padded to 128B lines

__device__ __forceinline__ unsigned short f2bf(float f) {
  unsigned u = __float_as_uint(f);
  u = u + 0x7FFFu + ((u >> 16) & 1u);  // RNE
  return (unsigned short)(u >> 16);
}
__device__ __forceinline__ unsigned fenc(float f) {
  unsigned u = __float_as_uint(f);
  return (u & 0x80000000u) ? ~u : (u | 0x80000000u);
}
// device-scope relaxed atomics (coherent, no cache-maintenance ops)
__device__ __forceinline__ float ldf(const float* p) {
  return __hip_atomic_load(p, __ATOMIC_RELAXED, __HIP_MEMORY_SCOPE_AGENT);
}
__device__ __forceinline__ void stf(float* p, float v) {
  __hip_atomic_store(p, v, __ATOMIC_RELAXED, __HIP_MEMORY_SCOPE_AGENT);
}
__device__ __forceinline__ u64 ld8(const void* p) {
  return __hip_atomic_load((const u64*)p, __ATOMIC_RELAXED, __HIP_MEMORY_SCOPE_AGENT);
}
__device__ __forceinline__ int ldflag(const int* p) {
  return __hip_atomic_load(p, __ATOMIC_RELAXED, __HIP_MEMORY_SCOPE_AGENT);
}
__device__ __forceinline__ void stflag(int* p, int v) {
  __hip_atomic_store(p, v, __ATOMIC_RELAXED, __HIP_MEMORY_SCOPE_AGENT);
}

// R4 hierarchical fence-free barrier.
// Visibility chain (all via LLC, the device coherence point): data stores drained
// (s_waitcnt 0) before arrival store; master's poll load of arrival=ep implies data
// at LLC; master's release store follows its poll loads; poller's load of release=ep
// implies everything at LLC; subsequent sc loads see fresh data. Epochs strictly
// increase per release line across all dispatches -> stale values never >= ep.
// Release lines: index 256 + (first>>5), +8 variant for full-grid (count==256).
__device__ __forceinline__ void wgbar(int* flags, int wg, int first, int count, unsigned ep) {
  __atomic_signal_fence(__ATOMIC_SEQ_CST);
  __builtin_amdgcn_s_waitcnt(0);  // per-wave: sc-stores reached the coherent point
  __syncthreads();
  const int tid = threadIdx.x;
  if (tid == 0) stflag(&flags[wg * FPAD], (int)ep);
  int* rel = &flags[(256 + (first >> 5) + (count == 256 ? 8 : 0)) * FPAD];
  if (wg == first) {  // master: poll group arrivals, publish release
    if (tid < 64) {
      for (int f = first + tid; f < first + count; f += 64) {
        while ((unsigned)ldflag(&flags[f * FPAD]) < ep) __builtin_amdgcn_s_sleep(1);
      }
    }
    __syncthreads();
    if (tid == 0) stflag(rel, (int)ep);
  } else if (tid == 0) {
    while ((unsigned)ldflag(rel) < ep) __builtin_amdgcn_s_sleep(4);
  }
  __atomic_signal_fence(__ATOMIC_SEQ_CST);
  __syncthreads();
}

// ---------------- W_fc fp32 -> bf16 ----------------
__global__ void k_wfcb(const float* __restrict__ W, unsigned short* __restrict__ Wb) {
  const int n = NV * HID;
  for (int i = ((int)blockIdx.x * 256 + (int)threadIdx.x) * 8; i < n; i += 2048 * 256 * 8) {
    v4f a = *(const v4f*)(W + i);
    v4f b = *(const v4f*)(W + i + 4);
    short8 o;
    o[0] = (short)f2bf(a[0]); o[1] = (short)f2bf(a[1]);
    o[2] = (short)f2bf(a[2]); o[3] = (short)f2bf(a[3]);
    o[4] = (short)f2bf(b[0]); o[5] = (short)f2bf(b[1]);
    o[6] = (short)f2bf(b[2]); o[7] = (short)f2bf(b[3]);
    *(short8*)(Wb + i) = o;
  }
}

// ---------------- fp32 GEMM: P[i][j] = sum_k A[i][k]*W[j][k] + bias[j] ----------------
template <int GATHER>
__global__ __launch_bounds__(256, 2) void k_gemm(const float* __restrict__ A,
                                                 const int* __restrict__ xtok,
                                                 const float* __restrict__ emb,
                                                 const float* __restrict__ W,
                                                 const float* __restrict__ bias,
                                                 float* __restrict__ P) {
  __shared__ __align__(16) float As[32 * 132];
  __shared__ __align__(16) float Bs[32 * 132];
  const int tid = threadIdx.x;
  const int i0 = ((int)blockIdx.x >> 2) * 128, j0 = ((int)blockIdx.x & 3) * 128;
  const int tx = tid & 15, ty = tid >> 4;
  float acc[8][8] = {};
  const int sa = 4 * ((tx >> 2) & 1);
  const int sb = 4 * ((ty >> 2) & 1);
  const int pa0 = (tx * 8) ^ sa, pa1 = (tx * 8 + 4) ^ sa;
  const int pb0 = (ty * 8) ^ sb, pb1 = (ty * 8 + 4) ^ sb;
  for (int kc = 0; kc < HID; kc += 32) {
#pragma unroll
    for (int u = 0; u < 4; u++) {
      int lin = tid + u * 256;
      int il = lin >> 3, kq = (lin & 7) * 4;
      int pi = il ^ (4 * ((il >> 5) & 1));
      const float* asrc;
      if (GATHER) {
        int row = i0 + il;
        int tok = xtok[(row & 63) * SEQL + (row >> 6)];  // x[b][t], row = t*64+b
        asrc = emb + (size_t)tok * HID + kc + kq;
      } else {
        asrc = A + (size_t)(i0 + il) * HID + kc + kq;
      }
      v4f av = *(const v4f*)asrc;
      v4f bv = *(const v4f*)(W + (size_t)(j0 + il) * HID + kc + kq);
      As[(kq + 0) * 132 + pi] = av[0]; As[(kq + 1) * 132 + pi] = av[1];
      As[(kq + 2) * 132 + pi] = av[2]; As[(kq + 3) * 132 + pi] = av[3];
      Bs[(kq + 0) * 132 + pi] = bv[0]; Bs[(kq + 1) * 132 + pi] = bv[1];
      Bs[(kq + 2) * 132 + pi] = bv[2]; Bs[(kq + 3) * 132 + pi] = bv[3];
    }
    __syncthreads();
#pragma unroll 8
    for (int k = 0; k < 32; k++) {
      v4f a0 = *(const v4f*)&As[k * 132 + pa0];
      v4f a1 = *(const v4f*)&As[k * 132 + pa1];
      v4f b0 = *(const v4f*)&Bs[k * 132 + pb0];
      v4f b1 = *(const v4f*)&Bs[k * 132 + pb1];
      float ar[8] = {a0[0], a0[1], a0[2], a0[3], a1[0], a1[1], a1[2], a1[3]};
      float br[8] = {b0[0], b0[1], b0[2], b0[3], b1[0], b1[1], b1[2], b1[3]};
#pragma unroll
      for (int r = 0; r < 8; r++)
#pragma unroll
        for (int c = 0; c < 8; c++) acc[r][c] = fmaf(ar[r], br[c], acc[r][c]);
    }
    __syncthreads();
  }
  v4f bl0 = *(const v4f*)(bias + j0 + ty * 8);
  v4f bl1 = *(const v4f*)(bias + j0 + ty * 8 + 4);
#pragma unroll
  for (int r = 0; r < 8; r++) {
    float* dst = P + (size_t)(i0 + tx * 8 + r) * HID + j0 + ty * 8;
    v4f o0 = {acc[r][0] + bl0[0], acc[r][1] + bl0[1], acc[r][2] + bl0[2], acc[r][3] + bl0[3]};
    v4f o1 = {acc[r][4] + bl1[0], acc[r][5] + bl1[1], acc[r][6] + bl1[2], acc[r][7] + bl1[3]};
    *(v4f*)dst = o0;
    *(v4f*)(dst + 4) = o1;
  }
}

// ---------------- persistent recurrence scan ----------------
// 256 wgs = 8 batch-groups (8 batches) x 32 j-groups (16 neurons); Whh slice in VGPRs.
__global__ __launch_bounds__(256, 2) void k_scan(float* __restrict__ P,
                                                 const float* __restrict__ Whh,
                                                 const float* __restrict__ bhh,
                                                 float* __restrict__ hbuf,
                                                 int* __restrict__ flags, int store_h,
                                                 unsigned ep) {
  __shared__ __align__(16) float hs[32 * 132];
  const int wg = blockIdx.x, tid = threadIdx.x;
  const int bg = wg >> 5, jg = wg & 31;
  const int b0 = bg * 8, j0 = jg * 16;
  const int bh = tid & 1, jg2 = (tid >> 1) & 3, ks = tid >> 3;
  v4f wv[4][4];
#pragma unroll
  for (int jj = 0; jj < 4; jj++)
#pragma unroll
    for (int i4 = 0; i4 < 4; i4++)
      wv[jj][i4] = *(const v4f*)(Whh + (size_t)(j0 + jg2 * 4 + jj) * HID + ks * 16 + i4 * 4);
  for (int t = 0; t < SEQL; t++) {
    const int p = t & 1;
    float* Pt = P + (size_t)t * BH;
    const float* hsrc = hbuf + p * BH + b0 * HID;
#pragma unroll
    for (int u = 0; u < 16; u++) {
      int lin = tid + u * 256;
      int b = lin >> 9, k = lin & 511;
      hs[(k >> 4) * 132 + b * 16 + (k & 15)] = ldf(hsrc + b * HID + k);
    }
    __syncthreads();
    float acc[4][4] = {};
#pragma unroll
    for (int i4 = 0; i4 < 4; i4++) {
#pragma unroll
      for (int bb = 0; bb < 4; bb++) {
        int b = bh * 4 + bb;
        v4f hv = *(const v4f*)&hs[ks * 132 + b * 16 + i4 * 4];
#pragma unroll
        for (int jj = 0; jj < 4; jj++) {
          float a = acc[bb][jj];
          a = fmaf(hv[0], wv[jj][i4][0], a);
          a = fmaf(hv[1], wv[jj][i4][1], a);
          a = fmaf(hv[2], wv[jj][i4][2], a);
          a = fmaf(hv[3], wv[jj][i4][3], a);
          acc[bb][jj] = a;
        }
      }
    }
    __syncthreads();  // reuse hs as partials [ks32][b8][j16]
#pragma unroll
    for (int bb = 0; bb < 4; bb++) {
      v4f pv = {acc[bb][0], acc[bb][1], acc[bb][2], acc[bb][3]};
      *(v4f*)&hs[ks * 132 + (bh * 4 + bb) * 16 + jg2 * 4] = pv;
    }
    __syncthreads();
    if (tid < 128) {
      int bb = tid >> 4, jj = tid & 15;
      float sum = 0.f;
#pragma unroll
      for (int k2 = 0; k2 < 32; k2++) sum += hs[k2 * 132 + bb * 16 + jj];
      int jglob = j0 + jj, bglob = b0 + bb;
      float z = Pt[bglob * HID + jglob] + bhh[jglob] + sum;
      float h = tanhf(z);
      stf(&hbuf[(p ^ 1) * BH + bglob * HID + jglob], h);
      if (store_h) Pt[bglob * HID + jglob] = h;  // H history for layer-1 GEMM (next kernel)
    }
    wgbar(flags, wg, bg * 32, 32, ++ep);
  }
}

// R3: issue one 32KB Wfcb k-tile (128 cols x 128 k, bf16) into LDS via global_load_lds.
// Per wave: 8 x dwordx4, per-lane pre-swizzled global source so the LDS image is the
// exact per-lane MFMA B-fragment stream: [wave 8KB][kc_sub 2KB][fq 1KB][lane 16B].
__device__ __forceinline__ void issue_tile(const unsigned short* __restrict__ Wfcb,
                                           float* buf, int wg, int tid, int T) {
  const int wv = tid >> 6, ln = tid & 63;
  const unsigned short* sb =
      Wfcb + (size_t)(wg * 128 + wv * 32 + (ln & 15)) * HID + T * 128 + (ln >> 4) * 8;
#pragma unroll
  for (int kc = 0; kc < 4; kc++)
#pragma unroll
    for (int fq = 0; fq < 2; fq++)
      __builtin_amdgcn_global_load_lds(
          (const unsigned int*)(sb + (size_t)fq * 16 * HID + kc * 32),
          (unsigned int*)(buf + wv * 2048 + kc * 512 + fq * 256), 16, 0, 0);
}

// ---------------- persistent decoder ----------------
__global__ __launch_bounds__(256, 1) void k_decoder(
    const float* __restrict__ emb, const float* __restrict__ Wih, const float* __restrict__ Whh,
    const float* __restrict__ bih, const float* __restrict__ bhh, const float* __restrict__ Wfc,
    const float* __restrict__ bfc, const unsigned short* __restrict__ Wfcb,
    float* __restrict__ h0buf, float* __restrict__ h1buf, unsigned short* __restrict__ h1bf,
    float* __restrict__ pmaxp, unsigned long long* __restrict__ best, int* __restrict__ flags,
    float* __restrict__ out, unsigned ep) {
  __shared__ __align__(16) float Wl[4 * 4224];  // [ih0,hh0,ih1,hh1][ks32][j8][k16]+pad
  __shared__ __align__(16) float es[32 * 268];  // stage / partials / C: tile buf0 / pmr / red
  __shared__ __align__(16) float hss[32 * 268]; // stage / C: tile buf1 / E: h-row cache
  const int wg = blockIdx.x, tid = threadIdx.x;
  const int bg = wg >> 6, jgD = wg & 63;
  const int bh = tid & 3, jg2 = (tid >> 2) & 1, ks = tid >> 3;
  for (int m = 0; m < 4; m++) {
    const float* src = ((m & 1) ? Whh : Wih) + (size_t)(m >> 1) * HID * HID;
#pragma unroll
    for (int u = 0; u < 4; u++) {
      int lin = tid + u * 256;
      int j = lin >> 7, k4 = (lin & 127) * 4;
      v4f v = *(const v4f*)(src + (size_t)(jgD * 8 + j) * HID + k4);
      *(v4f*)&Wl[m * 4224 + (k4 >> 4) * 132 + j * 16 + (k4 & 15)] = v;
    }
  }
  for (int st = 0; st < TDEC; st++) {
    const int p = st & 1;
    // ---- phases A (l0) / B (l1) ----
    for (int ph = 0; ph < 2; ph++) {
      if (ph == 0) {
        // es <- emb[tok] (plain input, vectorized); hss <- h0 slot p (atomic)
#pragma unroll
        for (int u = 0; u < 8; u++) {
          int lin = tid + u * 256;
          int b = lin >> 7, k4 = (lin & 127) * 4;
          unsigned vtok = 0u;
          if (st > 0) {
            u64 kk = ld8(&best[bg * 16 + b]);
            vtok = 0xFFFFFFFFu - (unsigned)(kk & 0xFFFFFFFFull);
            if (vtok >= (unsigned)NV) vtok = 0u;
          }
          v4f av = *(const v4f*)(emb + (size_t)vtok * HID + k4);
          *(v4f*)&es[(k4 >> 4) * 268 + b * 16 + (k4 & 15)] = av;
        }
#pragma unroll
        for (int u = 0; u < 32; u++) {
          int lin = tid + u * 256;
          int b = lin >> 9, k = lin & 511;
          hss[(k >> 4) * 268 + b * 16 + (k & 15)] = ldf(h0buf + p * BH + (bg * 16 + b) * HID + k);
        }
      } else {
#pragma unroll
        for (int u = 0; u < 32; u++) {
          int lin = tid + u * 256;
          int b = lin >> 9, k = lin & 511;
          int off = (k >> 4) * 268 + b * 16 + (k & 15);
          int row = (bg * 16 + b) * HID + k;
          es[off] = ldf(h0buf + (p ^ 1) * BH + row);
          hss[off] = ldf(h1buf + p * BH + row);
        }
      }
      __syncthreads();
      float acc[4][4] = {};
      const float* Wi = &Wl[(ph * 2 + 0) * 4224];
      const float* Wh = &Wl[(ph * 2 + 1) * 4224];
#pragma unroll
      for (int i4 = 0; i4 < 4; i4++) {
        v4f wi[4], wh[4];
#pragma unroll
        for (int jj = 0; jj < 4; jj++) {
          wi[jj] = *(const v4f*)&Wi[ks * 132 + (jg2 * 4 + jj) * 16 + i4 * 4];
          wh[jj] = *(const v4f*)&Wh[ks * 132 + (jg2 * 4 + jj) * 16 + i4 * 4];
        }
#pragma unroll
        for (int bb = 0; bb < 4; bb++) {
          int b = bh * 4 + bb;
          v4f evv = *(const v4f*)&es[ks * 268 + b * 16 + i4 * 4];
          v4f hvv = *(const v4f*)&hss[ks * 268 + b * 16 + i4 * 4];
#pragma unroll
          for (int jj = 0; jj < 4; jj++) {
            float a = acc[bb][jj];
            a = fmaf(evv[0], wi[jj][0], a); a = fmaf(evv[1], wi[jj][1], a);
            a = fmaf(evv[2], wi[jj][2], a); a = fmaf(evv[3], wi[jj][3], a);
            a = fmaf(hvv[0], wh[jj][0], a); a = fmaf(hvv[1], wh[jj][1], a);
            a = fmaf(hvv[2], wh[jj][2], a); a = fmaf(hvv[3], wh[jj][3], a);
            acc[bb][jj] = a;
          }
        }
      }
      __syncthreads();  // partials alias es: [ks32][b16][j8]
#pragma unroll
      for (int bb = 0; bb < 4; bb++) {
        v4f pv = {acc[bb][0], acc[bb][1], acc[bb][2], acc[bb][3]};
        *(v4f*)&es[ks * 132 + (bh * 4 + bb) * 8 + jg2 * 4] = pv;
      }
      __syncthreads();
      if (tid < 128) {
        int b = tid >> 3, j = tid & 7;
        float sum = 0.f;
#pragma unroll
        for (int k2 = 0; k2 < 32; k2++) sum += es[k2 * 132 + b * 8 + j];
        int jglob = jgD * 8 + j, bglob = bg * 16 + b;
        float z = bih[ph * HID + jglob] + bhh[ph * HID + jglob] + sum;
        float h = tanhf(z);
        float* hb = (ph ? h1buf : h0buf);
        stf(&hb[(p ^ 1) * BH + bglob * HID + jglob], h);
        if (ph) {  // pack bf16 pairs, even-j lanes store 4B
          unsigned hbv = f2bf(h);
          unsigned nb = (unsigned)__shfl_down((int)hbv, 1);
          if ((j & 1) == 0)
            __hip_atomic_store((unsigned*)(h1bf + (size_t)bglob * HID + jglob),
                               hbv | (nb << 16), __ATOMIC_RELAXED, __HIP_MEMORY_SCOPE_AGENT);
        }
      }
      if (ph == 0) {
        wgbar(flags, wg, bg * 64, 64, ++ep);
      } else {
        // full hierarchical barrier, with phase-C tile-0 prefetch issued between
        // arrival and poll. es reads are complete before the internal __syncthreads,
        // so the async LDS writes of tile 0 cannot race phase B.
        ++ep;
        __atomic_signal_fence(__ATOMIC_SEQ_CST);
        __builtin_amdgcn_s_waitcnt(0);
        __syncthreads();
        if (tid == 0) stflag(&flags[wg * FPAD], (int)ep);
        if (wg < 250) issue_tile(Wfcb, es, wg, tid, 0);
        int* rel = &flags[(256 + 8) * FPAD];
        if (wg == 0) {
          if (tid < 64) {
            for (int f = tid; f < 256; f += 64) {
              while ((unsigned)ldflag(&flags[f * FPAD]) < ep) __builtin_amdgcn_s_sleep(1);
            }
          }
          __syncthreads();
          if (tid == 0) stflag(rel, (int)ep);
        } else if (tid == 0) {
          while ((unsigned)ldflag(rel) < ep) __builtin_amdgcn_s_sleep(4);
        }
        __atomic_signal_fence(__ATOMIC_SEQ_CST);
        __syncthreads();
      }
    }
    // ---- phase C: logits = h1 @ Wfc^T + bfc (bf16 MFMA, Wfcb via LDS double-buffer);
    //      wg250 resets best ----
    if (wg < 250) {
      const int w = tid >> 6, lane = tid & 63;
      const int l16 = lane & 15, quad = lane >> 4;
      const int n0 = wg * 128 + w * 32;
      const int nc0 = n0 + l16, nc1 = n0 + 16 + l16;
      const float bf0 = bfc[nc0], bf1 = bfc[nc1];
      v4f acc[4][2] = {};
#pragma unroll
      for (int t = 0; t < 4; t++) {
        const float* buf = (t & 1) ? hss : es;
        // hoist this k-tile's A-fragments (h rows, bf16) into regs: 32 ld8, issued
        // BEFORE tile t+1 so that vmcnt(8) (in-order) implies tile t's 8 LDS-loads done.
        union { u64 q[2]; short8 s; } au[4][4];
#pragma unroll
        for (int mb = 0; mb < 4; mb++) {
          const unsigned short* hr = h1bf + (size_t)(mb * 16 + l16) * HID + t * 128 + quad * 8;
#pragma unroll
          for (int kc = 0; kc < 4; kc++) {
            au[mb][kc].q[0] = ld8(hr + kc * 32);
            au[mb][kc].q[1] = ld8(hr + kc * 32 + 4);
          }
        }
        __builtin_amdgcn_sched_barrier(0);
        if (t < 3) issue_tile(Wfcb, (t & 1) ? es : hss, wg, tid, t + 1);
        __builtin_amdgcn_sched_barrier(0);
        // >=40 ops are younger than tile t's loads here, so vmcnt(8) guarantees tile t
        // is in LDS while tile t+1 (the youngest 8) stays in flight.
        if (t < 3) asm volatile("s_waitcnt vmcnt(8)" ::: "memory");
        else       asm volatile("s_waitcnt vmcnt(0)" ::: "memory");
        __builtin_amdgcn_sched_barrier(0);
#pragma unroll
        for (int kc = 0; kc < 4; kc++) {
          short8 b0 = *(const short8*)(buf + w * 2048 + kc * 512 + lane * 4);
          short8 b1 = *(const short8*)(buf + w * 2048 + kc * 512 + 256 + lane * 4);
#pragma unroll
          for (int mb = 0; mb < 4; mb++) {
            acc[mb][0] =
                __builtin_amdgcn_mfma_f32_16x16x32_bf16(au[mb][kc].s, b0, acc[mb][0], 0, 0, 0);
            acc[mb][1] =
                __builtin_amdgcn_mfma_f32_16x16x32_bf16(au[mb][kc].s, b1, acc[mb][1], 0, 0, 0);
          }
        }
      }
      __syncthreads();  // all waves done reading tile bufs before pmr aliases es
      float* pmr = es;  // [4 waves][64 rows]
#pragma unroll
      for (int mb = 0; mb < 4; mb++) {
#pragma unroll
        for (int r = 0; r < 4; r++) {
          float v0 = acc[mb][0][r] + bf0;
          float v1 = acc[mb][1][r] + bf1;
          int m = mb * 16 + quad * 4 + r;  // C/D: col=lane&15, row=quad*4+reg
          stf(&out[(size_t)(m * TDEC + st) * NV + nc0], v0);
          stf(&out[(size_t)(m * TDEC + st) * NV + nc1], v1);
          float mx = fmaxf(v0, v1);
          mx = fmaxf(mx, __shfl_xor(mx, 1));
          mx = fmaxf(mx, __shfl_xor(mx, 2));
          mx = fmaxf(mx, __shfl_xor(mx, 4));
          mx = fmaxf(mx, __shfl_xor(mx, 8));
          if (l16 == 0) pmr[w * 64 + m] = mx;
        }
      }
      __syncthreads();
      if (tid < 64) {
        float m4 = fmaxf(fmaxf(pmr[tid], pmr[64 + tid]), fmaxf(pmr[128 + tid], pmr[192 + tid]));
        stf(&pmaxp[tid * 256 + wg], m4);  // R4: b-major so phase E reads contiguously
      }
    } else if (wg == 250 && tid < 64) {
      // safe window: after B's full barrier (all A reads of best done), before E's atomicMax
      __hip_atomic_store(&best[tid], 0ull, __ATOMIC_RELAXED, __HIP_MEMORY_SCOPE_AGENT);
    }
    wgbar(flags, wg, 0, 256, ++ep);
    // ---- phase E: candidate refine + argmax; wg = b*4 + quarter ----
    {
      const int b = wg >> 2, q = wg & 3;
      const float* hrow = h1buf + (p ^ 1) * BH + b * HID;
      hss[tid] = ldf(hrow + tid);
      hss[tid + 256] = ldf(hrow + tid + 256);
      float* red = es;
      red[tid] = (tid < 250) ? ldf(&pmaxp[b * 256 + tid]) : -3.0e38f;  // R4: contiguous
      __syncthreads();
      for (int o = 128; o > 0; o >>= 1) {
        if (tid < o) red[tid] = fmaxf(red[tid], red[tid + o]);
        __syncthreads();
      }
      const float thr = red[0] - 0.05f;
      const size_t ob = (size_t)(b * TDEC + st) * NV + q * 8000;
      for (int i = tid * 2; i < 8000; i += 512) {
        u64 qq = ld8(out + ob + i);
        float lv[2] = {__uint_as_float((unsigned)qq), __uint_as_float((unsigned)(qq >> 32))};
#pragma unroll
        for (int c = 0; c < 2; c++) {
          if (lv[c] >= thr) {
            int vidx = q * 8000 + i + c;
            const v4f* h4 = (const v4f*)hss;
            const v4f* w4 = (const v4f*)(Wfc + (size_t)vidx * HID);
            v4f s0 = 0, s1 = 0;
            for (int k = 0; k < 128; k += 2) {
              s0 += h4[k] * w4[k];
              s1 += h4[k + 1] * w4[k + 1];
            }
            v4f sv = s0 + s1;
            float d = bfc[vidx] + sv[0] + sv[1] + sv[2] + sv[3];
            u64 key = ((u64)fenc(d) << 32) | (u64)(0xFFFFFFFFu - (unsigned)vidx);
            atomicMax(&best[b], key);
          }
        }
      }
    }
    // last step: full-grid barrier so the h_fin epilogue sees every group's final h
    if (st == TDEC - 1) wgbar(flags, wg, 0, 256, ++ep);
    else                wgbar(flags, wg, bg * 64, 64, ++ep);
  }
  // h_fin: [2][64][512] appended after logits (final h lives in slot 0)
  int lin = wg * 256 + tid;
  int l = lin >> 15, r2 = lin & 32767;
  out[65536000 + lin] = ldf(&(l ? h1buf : h0buf)[r2]);
}

extern "C" void kernel_launch(void* const* d_in, const int* in_sizes, int n_in, void* d_out,
                              int out_size, void* d_ws, size_t ws_size, hipStream_t stream) {
  const int* x = (const int*)d_in[0];
  const float* emb = (const float*)d_in[1];
  const float* Wih = (const float*)d_in[2];
  const float* Whh = (const float*)d_in[3];
  const float* bih = (const float*)d_in[4];
  const float* bhh = (const float*)d_in[5];
  const float* Wfc = (const float*)d_in[6];
  const float* bfc = (const float*)d_in[7];
  float* out = (float*)d_out;
  char* ws = (char*)d_ws;

  float* P0 = (float*)ws;                          // [256][64][512] -> becomes H0 in-place
  float* P1 = P0 + (size_t)SEQL * BH;              // [256][64][512]
  unsigned short* Wfcb = (unsigned short*)(P1 + (size_t)SEQL * BH);  // [32000][512] bf16
  char* small = (char*)(Wfcb + (size_t)NV * HID);
  float* h0buf = (float*)small;                    // [2][64][512]
  float* h1buf = h0buf + 2 * BH;                   // [2][64][512]
  unsigned short* h1bf = (unsigned short*)(h1buf + 2 * BH);  // [64][512] bf16
  float* pmaxp = (float*)(h1bf + BH);              // [64 b][256 wg] (b-major, R4)
  unsigned long long* best = (unsigned long long*)(pmaxp + 256 * 64);  // [64]
  int* flags = (int*)(best + 64);                  // [(256 arrivals + 16 release)*FPAD]
  size_t small_bytes = (size_t)2 * BH * 4 + (size_t)2 * BH * 4 + BH * 2 + 256 * 64 * 4 +
                       64 * 8 + (256 + 16) * FPAD * 4;

  hipMemsetAsync(small, 0, small_bytes, stream);  // h=0, best=0, flags epoch 0
  k_wfcb<<<2048, 256, 0, stream>>>(Wfc, Wfcb);
  // encoder layer0 ih-part: P0 = gather(emb, x) @ Wih0^T + bih0
  k_gemm<1><<<512, 256, 0, stream>>>(nullptr, x, emb, Wih, bih, P0);
  // layer0 scan (stores H0 in-place into P0); final h0 -> h0buf slot 0
  k_scan<<<256, 256, 0, stream>>>(P0, Whh, bhh, h0buf, flags, 1, 0u);
  // layer1 ih-part: P1 = H0 @ Wih1^T + bih1
  k_gemm<0><<<512, 256, 0, stream>>>(P0, nullptr, nullptr, Wih + 262144, bih + 512, P1);
  // layer1 scan; final h1 -> h1buf slot 0
  k_scan<<<256, 256, 0, stream>>>(P1, Whh + 262144, bhh + 512, h1buf, flags, 0, 256u);
  // decoder: 32 greedy steps + h_fin epilogue
  k_decoder<<<256, 256, 0, stream>>>(emb, Wih, Whh, bih, bhh, Wfc, bfc, Wfcb, h0buf, h1buf,
                                     h1bf, pmaxp, best, flags, out, 512u);
}

// Round 5
// 6529.178 us; speedup vs baseline: 1.1734x; 1.1734x over previous
//
#include <hip/hip_runtime.h>
#include <hip/hip_bf16.h>

// trajectory2seq: 2-layer Elman RNN encoder (SEQ=256) + greedy decoder (32 steps)
//  - encoder ih-parts hoisted into two big fp32 GEMMs (k_gemm)
//  - persistent scan kernels for the hh-recurrence (weights in VGPRs, flag barriers)
// R3: logits Wfcb strip double-buffered through LDS (global_load_lds, counted vmcnt).
// R4: hierarchical barriers for the scans (kept); decoder barrier variants measured
//     IDENTICAL (flat vs hierarchical) -> poll-contention theory refuted.
// R5: decoder de-persisted. The persistent decoder burned ~110us/step with ALL pipes
// idle (VALU 3%, MFMA 0.7%, HBM 7%) and was insensitive to barrier implementation.
// Now each phase is its own stream-ordered dispatch (32 steps x {cell0, cell1,
// logits, argmax} + h_fin epilogue). Kernel boundaries give cross-wg visibility for
// free: all h/token exchange via normal L2-cached loads/stores (no sc-bypass atomics,
// no s_waitcnt(0) drains, no flag polling). Also serves as the phase ablation: each
// phase kernel now reports its own dur_us in rocprof.

typedef float v4f __attribute__((ext_vector_type(4)));
typedef short short8 __attribute__((ext_vector_type(8)));
typedef unsigned long long u64;

#define HID 512
#define NBAT 64
#define SEQL 256
#define NV 32000
#define TDEC 32
#define BH (64 * 512)
#define FPAD 32  // flags padded to 128B lines

__device__ __forceinline__ unsigned short f2bf(float f) {
  unsigned u = __float_as_uint(f);
  u = u + 0x7FFFu + ((u >> 16) & 1u);  // RNE
  return (unsigned short)(u >> 16);
}
__device__ __forceinline__ unsigned fenc(float f) {
  unsigned u = __float_as_uint(f);
  return (u & 0x80000000u) ? ~u : (u | 0x80000000u);
}
// device-scope relaxed atomics (scan-internal h exchange only)
__device__ __forceinline__ float ldf(const float* p) {
  return __hip_atomic_load(p, __ATOMIC_RELAXED, __HIP_MEMORY_SCOPE_AGENT);
}
__device__ __forceinline__ void stf(float* p, float v) {
  __hip_atomic_store(p, v, __ATOMIC_RELAXED, __HIP_MEMORY_SCOPE_AGENT);
}
__device__ __forceinline__ int ldflag(const int* p) {
  return __hip_atomic_load(p, __ATOMIC_RELAXED, __HIP_MEMORY_SCOPE_AGENT);
}
__device__ __forceinline__ void stflag(int* p, int v) {
  __hip_atomic_store(p, v, __ATOMIC_RELAXED, __HIP_MEMORY_SCOPE_AGENT);
}

// hierarchical fence-free barrier (R4), used by the persistent scans only.
__device__ __forceinline__ void wgbar(int* flags, int wg, int first, int count, unsigned ep) {
  __atomic_signal_fence(__ATOMIC_SEQ_CST);
  __builtin_amdgcn_s_waitcnt(0);
  __syncthreads();
  const int tid = threadIdx.x;
  if (tid == 0) stflag(&flags[wg * FPAD], (int)ep);
  int* rel = &flags[(256 + (first >> 5) + (count == 256 ? 8 : 0)) * FPAD];
  if (wg == first) {
    if (tid < 64) {
      for (int f = first + tid; f < first + count; f += 64) {
        while ((unsigned)ldflag(&flags[f * FPAD]) < ep) __builtin_amdgcn_s_sleep(1);
      }
    }
    __syncthreads();
    if (tid == 0) stflag(rel, (int)ep);
  } else if (tid == 0) {
    while ((unsigned)ldflag(rel) < ep) __builtin_amdgcn_s_sleep(4);
  }
  __atomic_signal_fence(__ATOMIC_SEQ_CST);
  __syncthreads();
}

// ---------------- W_fc fp32 -> bf16 ----------------
__global__ void k_wfcb(const float* __restrict__ W, unsigned short* __restrict__ Wb) {
  const int n = NV * HID;
  for (int i = ((int)blockIdx.x * 256 + (int)threadIdx.x) * 8; i < n; i += 2048 * 256 * 8) {
    v4f a = *(const v4f*)(W + i);
    v4f b = *(const v4f*)(W + i + 4);
    short8 o;
    o[0] = (short)f2bf(a[0]); o[1] = (short)f2bf(a[1]);
    o[2] = (short)f2bf(a[2]); o[3] = (short)f2bf(a[3]);
    o[4] = (short)f2bf(b[0]); o[5] = (short)f2bf(b[1]);
    o[6] = (short)f2bf(b[2]); o[7] = (short)f2bf(b[3]);
    *(short8*)(Wb + i) = o;
  }
}

// ---------------- fp32 GEMM: P[i][j] = sum_k A[i][k]*W[j][k] + bias[j] ----------------
template <int GATHER>
__global__ __launch_bounds__(256, 2) void k_gemm(const float* __restrict__ A,
                                                 const int* __restrict__ xtok,
                                                 const float* __restrict__ emb,
                                                 const float* __restrict__ W,
                                                 const float* __restrict__ bias,
                                                 float* __restrict__ P) {
  __shared__ __align__(16) float As[32 * 132];
  __shared__ __align__(16) float Bs[32 * 132];
  const int tid = threadIdx.x;
  const int i0 = ((int)blockIdx.x >> 2) * 128, j0 = ((int)blockIdx.x & 3) * 128;
  const int tx = tid & 15, ty = tid >> 4;
  float acc[8][8] = {};
  const int sa = 4 * ((tx >> 2) & 1);
  const int sb = 4 * ((ty >> 2) & 1);
  const int pa0 = (tx * 8) ^ sa, pa1 = (tx * 8 + 4) ^ sa;
  const int pb0 = (ty * 8) ^ sb, pb1 = (ty * 8 + 4) ^ sb;
  for (int kc = 0; kc < HID; kc += 32) {
#pragma unroll
    for (int u = 0; u < 4; u++) {
      int lin = tid + u * 256;
      int il = lin >> 3, kq = (lin & 7) * 4;
      int pi = il ^ (4 * ((il >> 5) & 1));
      const float* asrc;
      if (GATHER) {
        int row = i0 + il;
        int tok = xtok[(row & 63) * SEQL + (row >> 6)];  // x[b][t], row = t*64+b
        asrc = emb + (size_t)tok * HID + kc + kq;
      } else {
        asrc = A + (size_t)(i0 + il) * HID + kc + kq;
      }
      v4f av = *(const v4f*)asrc;
      v4f bv = *(const v4f*)(W + (size_t)(j0 + il) * HID + kc + kq);
      As[(kq + 0) * 132 + pi] = av[0]; As[(kq + 1) * 132 + pi] = av[1];
      As[(kq + 2) * 132 + pi] = av[2]; As[(kq + 3) * 132 + pi] = av[3];
      Bs[(kq + 0) * 132 + pi] = bv[0]; Bs[(kq + 1) * 132 + pi] = bv[1];
      Bs[(kq + 2) * 132 + pi] = bv[2]; Bs[(kq + 3) * 132 + pi] = bv[3];
    }
    __syncthreads();
#pragma unroll 8
    for (int k = 0; k < 32; k++) {
      v4f a0 = *(const v4f*)&As[k * 132 + pa0];
      v4f a1 = *(const v4f*)&As[k * 132 + pa1];
      v4f b0 = *(const v4f*)&Bs[k * 132 + pb0];
      v4f b1 = *(const v4f*)&Bs[k * 132 + pb1];
      float ar[8] = {a0[0], a0[1], a0[2], a0[3], a1[0], a1[1], a1[2], a1[3]};
      float br[8] = {b0[0], b0[1], b0[2], b0[3], b1[0], b1[1], b1[2], b1[3]};
#pragma unroll
      for (int r = 0; r < 8; r++)
#pragma unroll
        for (int c = 0; c < 8; c++) acc[r][c] = fmaf(ar[r], br[c], acc[r][c]);
    }
    __syncthreads();
  }
  v4f bl0 = *(const v4f*)(bias + j0 + ty * 8);
  v4f bl1 = *(const v4f*)(bias + j0 + ty * 8 + 4);
#pragma unroll
  for (int r = 0; r < 8; r++) {
    float* dst = P + (size_t)(i0 + tx * 8 + r) * HID + j0 + ty * 8;
    v4f o0 = {acc[r][0] + bl0[0], acc[r][1] + bl0[1], acc[r][2] + bl0[2], acc[r][3] + bl0[3]};
    v4f o1 = {acc[r][4] + bl1[0], acc[r][5] + bl1[1], acc[r][6] + bl1[2], acc[r][7] + bl1[3]};
    *(v4f*)dst = o0;
    *(v4f*)(dst + 4) = o1;
  }
}

// ---------------- persistent recurrence scan (unchanged) ----------------
__global__ __launch_bounds__(256, 2) void k_scan(float* __restrict__ P,
                                                 const float* __restrict__ Whh,
                                                 const float* __restrict__ bhh,
                                                 float* __restrict__ hbuf,
                                                 int* __restrict__ flags, int store_h,
                                                 unsigned ep) {
  __shared__ __align__(16) float hs[32 * 132];
  const int wg = blockIdx.x, tid = threadIdx.x;
  const int bg = wg >> 5, jg = wg & 31;
  const int b0 = bg * 8, j0 = jg * 16;
  const int bh = tid & 1, jg2 = (tid >> 1) & 3, ks = tid >> 3;
  v4f wv[4][4];
#pragma unroll
  for (int jj = 0; jj < 4; jj++)
#pragma unroll
    for (int i4 = 0; i4 < 4; i4++)
      wv[jj][i4] = *(const v4f*)(Whh + (size_t)(j0 + jg2 * 4 + jj) * HID + ks * 16 + i4 * 4);
  for (int t = 0; t < SEQL; t++) {
    const int p = t & 1;
    float* Pt = P + (size_t)t * BH;
    const float* hsrc = hbuf + p * BH + b0 * HID;
#pragma unroll
    for (int u = 0; u < 16; u++) {
      int lin = tid + u * 256;
      int b = lin >> 9, k = lin & 511;
      hs[(k >> 4) * 132 + b * 16 + (k & 15)] = ldf(hsrc + b * HID + k);
    }
    __syncthreads();
    float acc[4][4] = {};
#pragma unroll
    for (int i4 = 0; i4 < 4; i4++) {
#pragma unroll
      for (int bb = 0; bb < 4; bb++) {
        int b = bh * 4 + bb;
        v4f hv = *(const v4f*)&hs[ks * 132 + b * 16 + i4 * 4];
#pragma unroll
        for (int jj = 0; jj < 4; jj++) {
          float a = acc[bb][jj];
          a = fmaf(hv[0], wv[jj][i4][0], a);
          a = fmaf(hv[1], wv[jj][i4][1], a);
          a = fmaf(hv[2], wv[jj][i4][2], a);
          a = fmaf(hv[3], wv[jj][i4][3], a);
          acc[bb][jj] = a;
        }
      }
    }
    __syncthreads();
#pragma unroll
    for (int bb = 0; bb < 4; bb++) {
      v4f pv = {acc[bb][0], acc[bb][1], acc[bb][2], acc[bb][3]};
      *(v4f*)&hs[ks * 132 + (bh * 4 + bb) * 16 + jg2 * 4] = pv;
    }
    __syncthreads();
    if (tid < 128) {
      int bb = tid >> 4, jj = tid & 15;
      float sum = 0.f;
#pragma unroll
      for (int k2 = 0; k2 < 32; k2++) sum += hs[k2 * 132 + bb * 16 + jj];
      int jglob = j0 + jj, bglob = b0 + bb;
      float z = Pt[bglob * HID + jglob] + bhh[jglob] + sum;
      float h = tanhf(z);
      stf(&hbuf[(p ^ 1) * BH + bglob * HID + jglob], h);
      if (store_h) Pt[bglob * HID + jglob] = h;
    }
    wgbar(flags, wg, bg * 32, 32, ++ep);
  }
}

// issue one 32KB Wfcb k-tile (128 cols x 128 k, bf16) into LDS via global_load_lds.
// Per wave: 8 x dwordx4, per-lane pre-swizzled global source so the LDS image is the
// exact per-lane MFMA B-fragment stream: [wave 8KB][kc_sub 2KB][fq 1KB][lane 16B].
__device__ __forceinline__ void issue_tile(const unsigned short* __restrict__ Wfcb,
                                           float* buf, int wg, int tid, int T) {
  const int wv = tid >> 6, ln = tid & 63;
  const unsigned short* sb =
      Wfcb + (size_t)(wg * 128 + wv * 32 + (ln & 15)) * HID + T * 128 + (ln >> 4) * 8;
#pragma unroll
  for (int kc = 0; kc < 4; kc++)
#pragma unroll
    for (int fq = 0; fq < 2; fq++)
      __builtin_amdgcn_global_load_lds(
          (const unsigned int*)(sb + (size_t)fq * 16 * HID + kc * 32),
          (unsigned int*)(buf + wv * 2048 + kc * 512 + fq * 256), 16, 0, 0);
}

// ---------------- decoder phase kernels (R5: one dispatch per phase) ----------------
// Elman cell, one layer. grid 256: bg = wg>>6 (16 batches), jgD = wg&63 (8 neurons).
template <int PH>
__global__ __launch_bounds__(256, 1) void k_cell(
    const float* __restrict__ emb, const float* __restrict__ Wih,
    const float* __restrict__ Whh, const float* __restrict__ bih,
    const float* __restrict__ bhh, const u64* __restrict__ best,
    float* __restrict__ h0buf, float* __restrict__ h1buf,
    unsigned short* __restrict__ h1bf, int st) {
  __shared__ __align__(16) float Wl[2 * 4224];   // [ih,hh][ks32][j8][k16]+pad
  __shared__ __align__(16) float es[32 * 268];   // input stage / partials
  __shared__ __align__(16) float hss[32 * 268];  // h stage
  const int wg = blockIdx.x, tid = threadIdx.x;
  const int bg = wg >> 6, jgD = wg & 63;
  const int bh = tid & 3, jg2 = (tid >> 2) & 1, ks = tid >> 3;
  const int p = st & 1;
#pragma unroll
  for (int m = 0; m < 2; m++) {
    const float* src = (m ? Whh : Wih) + (size_t)PH * HID * HID;
#pragma unroll
    for (int u = 0; u < 4; u++) {
      int lin = tid + u * 256;
      int j = lin >> 7, k4 = (lin & 127) * 4;
      v4f v = *(const v4f*)(src + (size_t)(jgD * 8 + j) * HID + k4);
      *(v4f*)&Wl[m * 4224 + (k4 >> 4) * 132 + j * 16 + (k4 & 15)] = v;
    }
  }
  if (PH == 0) {
#pragma unroll
    for (int u = 0; u < 8; u++) {
      int lin = tid + u * 256;
      int b = lin >> 7, k4 = (lin & 127) * 4;
      unsigned vtok = 0u;
      if (st > 0) {
        u64 kk = best[bg * 16 + b];
        vtok = 0xFFFFFFFFu - (unsigned)(kk & 0xFFFFFFFFull);
        if (vtok >= (unsigned)NV) vtok = 0u;
      }
      v4f av = *(const v4f*)(emb + (size_t)vtok * HID + k4);
      *(v4f*)&es[(k4 >> 4) * 268 + b * 16 + (k4 & 15)] = av;
    }
#pragma unroll
    for (int u = 0; u < 32; u++) {
      int lin = tid + u * 256;
      int b = lin >> 9, k = lin & 511;
      hss[(k >> 4) * 268 + b * 16 + (k & 15)] = h0buf[p * BH + (bg * 16 + b) * HID + k];
    }
  } else {
#pragma unroll
    for (int u = 0; u < 32; u++) {
      int lin = tid + u * 256;
      int b = lin >> 9, k = lin & 511;
      int off = (k >> 4) * 268 + b * 16 + (k & 15);
      int row = (bg * 16 + b) * HID + k;
      es[off] = h0buf[(p ^ 1) * BH + row];
      hss[off] = h1buf[p * BH + row];
    }
  }
  __syncthreads();
  float acc[4][4] = {};
  const float* Wi = &Wl[0];
  const float* Wh = &Wl[4224];
#pragma unroll
  for (int i4 = 0; i4 < 4; i4++) {
    v4f wi[4], wh[4];
#pragma unroll
    for (int jj = 0; jj < 4; jj++) {
      wi[jj] = *(const v4f*)&Wi[ks * 132 + (jg2 * 4 + jj) * 16 + i4 * 4];
      wh[jj] = *(const v4f*)&Wh[ks * 132 + (jg2 * 4 + jj) * 16 + i4 * 4];
    }
#pragma unroll
    for (int bb = 0; bb < 4; bb++) {
      int b = bh * 4 + bb;
      v4f evv = *(const v4f*)&es[ks * 268 + b * 16 + i4 * 4];
      v4f hvv = *(const v4f*)&hss[ks * 268 + b * 16 + i4 * 4];
#pragma unroll
      for (int jj = 0; jj < 4; jj++) {
        float a = acc[bb][jj];
        a = fmaf(evv[0], wi[jj][0], a); a = fmaf(evv[1], wi[jj][1], a);
        a = fmaf(evv[2], wi[jj][2], a); a = fmaf(evv[3], wi[jj][3], a);
        a = fmaf(hvv[0], wh[jj][0], a); a = fmaf(hvv[1], wh[jj][1], a);
        a = fmaf(hvv[2], wh[jj][2], a); a = fmaf(hvv[3], wh[jj][3], a);
        acc[bb][jj] = a;
      }
    }
  }
  __syncthreads();  // partials alias es: [ks32][b16][j8]
#pragma unroll
  for (int bb = 0; bb < 4; bb++) {
    v4f pv = {acc[bb][0], acc[bb][1], acc[bb][2], acc[bb][3]};
    *(v4f*)&es[ks * 132 + (bh * 4 + bb) * 8 + jg2 * 4] = pv;
  }
  __syncthreads();
  if (tid < 128) {
    int b = tid >> 3, j = tid & 7;
    float sum = 0.f;
#pragma unroll
    for (int k2 = 0; k2 < 32; k2++) sum += es[k2 * 132 + b * 8 + j];
    int jglob = jgD * 8 + j, bglob = bg * 16 + b;
    float z = bih[PH * HID + jglob] + bhh[PH * HID + jglob] + sum;
    float h = tanhf(z);
    float* hb = (PH ? h1buf : h0buf);
    hb[(p ^ 1) * BH + bglob * HID + jglob] = h;
    if (PH) {  // pack bf16 pairs, even-j lanes store 4B
      unsigned hbv = f2bf(h);
      unsigned nb = (unsigned)__shfl_down((int)hbv, 1);
      if ((j & 1) == 0)
        *(unsigned*)(h1bf + (size_t)bglob * HID + jglob) = hbv | (nb << 16);
    }
  }
}

// logits = h1 @ Wfc^T + bfc (bf16 MFMA, Wfcb via LDS double-buffer) + per-wg col max.
// grid 251: wgs 0-249 work (128 vocab cols each); wg 250 resets best[] (safe: this
// step's k_cell<0> already consumed it; this step's k_argmax writes it next).
__global__ __launch_bounds__(256, 1) void k_logits(
    const unsigned short* __restrict__ Wfcb, const unsigned short* __restrict__ h1bf,
    const float* __restrict__ bfc, float* __restrict__ out, float* __restrict__ pmaxp,
    u64* __restrict__ best, int st) {
  __shared__ __align__(16) float tb0[8192];
  __shared__ __align__(16) float tb1[8192];
  __shared__ float pmr[256];
  const int wg = blockIdx.x, tid = threadIdx.x;
  if (wg == 250) {
    if (tid < 64) best[tid] = 0ull;
    return;
  }
  const int w = tid >> 6, lane = tid & 63;
  const int l16 = lane & 15, quad = lane >> 4;
  const int n0 = wg * 128 + w * 32;
  const int nc0 = n0 + l16, nc1 = n0 + 16 + l16;
  const float bf0 = bfc[nc0], bf1 = bfc[nc1];
  issue_tile(Wfcb, tb0, wg, tid, 0);
  v4f acc[4][2] = {};
#pragma unroll
  for (int t = 0; t < 4; t++) {
    __builtin_amdgcn_sched_barrier(0);
    const float* buf = (t & 1) ? tb1 : tb0;
    // hoist this k-tile's A-fragments (h rows, bf16) into regs BEFORE tile t+1, so
    // in-order vmcnt(8) implies tile t's 8 LDS-loads (and all au loads) complete.
    union { u64 q[2]; short8 s; } au[4][4];
#pragma unroll
    for (int mb = 0; mb < 4; mb++) {
      const unsigned short* hr = h1bf + (size_t)(mb * 16 + l16) * HID + t * 128 + quad * 8;
#pragma unroll
      for (int kc = 0; kc < 4; kc++) {
        au[mb][kc].q[0] = *(const u64*)(hr + kc * 32);
        au[mb][kc].q[1] = *(const u64*)(hr + kc * 32 + 4);
      }
    }
    __builtin_amdgcn_sched_barrier(0);
    if (t < 3) issue_tile(Wfcb, (t & 1) ? tb0 : tb1, wg, tid, t + 1);
    __builtin_amdgcn_sched_barrier(0);
    if (t < 3) asm volatile("s_waitcnt vmcnt(8)" ::: "memory");
    else       asm volatile("s_waitcnt vmcnt(0)" ::: "memory");
    __builtin_amdgcn_sched_barrier(0);
#pragma unroll
    for (int kc = 0; kc < 4; kc++) {
      short8 b0 = *(const short8*)(buf + w * 2048 + kc * 512 + lane * 4);
      short8 b1 = *(const short8*)(buf + w * 2048 + kc * 512 + 256 + lane * 4);
#pragma unroll
      for (int mb = 0; mb < 4; mb++) {
        acc[mb][0] =
            __builtin_amdgcn_mfma_f32_16x16x32_bf16(au[mb][kc].s, b0, acc[mb][0], 0, 0, 0);
        acc[mb][1] =
            __builtin_amdgcn_mfma_f32_16x16x32_bf16(au[mb][kc].s, b1, acc[mb][1], 0, 0, 0);
      }
    }
  }
#pragma unroll
  for (int mb = 0; mb < 4; mb++) {
#pragma unroll
    for (int r = 0; r < 4; r++) {
      float v0 = acc[mb][0][r] + bf0;
      float v1 = acc[mb][1][r] + bf1;
      int m = mb * 16 + quad * 4 + r;  // C/D: col=lane&15, row=quad*4+reg
      out[(size_t)(m * TDEC + st) * NV + nc0] = v0;
      out[(size_t)(m * TDEC + st) * NV + nc1] = v1;
      float mx = fmaxf(v0, v1);
      mx = fmaxf(mx, __shfl_xor(mx, 1));
      mx = fmaxf(mx, __shfl_xor(mx, 2));
      mx = fmaxf(mx, __shfl_xor(mx, 4));
      mx = fmaxf(mx, __shfl_xor(mx, 8));
      if (l16 == 0) pmr[w * 64 + m] = mx;
    }
  }
  __syncthreads();
  if (tid < 64) {
    float m4 = fmaxf(fmaxf(pmr[tid], pmr[64 + tid]), fmaxf(pmr[128 + tid], pmr[192 + tid]));
    pmaxp[tid * 256 + wg] = m4;  // b-major: phase E reads 250 contiguous floats
  }
}

// candidate refine + argmax. grid 256: wg = b*4 + quarter (8000 vocab each).
__global__ __launch_bounds__(256, 1) void k_argmax(
    const float* __restrict__ Wfc, const float* __restrict__ bfc,
    const float* __restrict__ h1buf, const float* __restrict__ pmaxp,
    const float* __restrict__ out, u64* __restrict__ best, int st) {
  __shared__ __align__(16) float hcache[512];
  __shared__ float red[256];
  const int wg = blockIdx.x, tid = threadIdx.x;
  const int b = wg >> 2, q = wg & 3;
  const int p = st & 1;
  const float* hrow = h1buf + (p ^ 1) * BH + b * HID;
  hcache[tid] = hrow[tid];
  hcache[tid + 256] = hrow[tid + 256];
  red[tid] = (tid < 250) ? pmaxp[b * 256 + tid] : -3.0e38f;
  __syncthreads();
  for (int o = 128; o > 0; o >>= 1) {
    if (tid < o) red[tid] = fmaxf(red[tid], red[tid + o]);
    __syncthreads();
  }
  const float thr = red[0] - 0.05f;
  const size_t ob = (size_t)(b * TDEC + st) * NV + q * 8000;
  for (int i = tid * 2; i < 8000; i += 512) {
    u64 qq = *(const u64*)(out + ob + i);
    float lv[2] = {__uint_as_float((unsigned)qq), __uint_as_float((unsigned)(qq >> 32))};
#pragma unroll
    for (int c = 0; c < 2; c++) {
      if (lv[c] >= thr) {
        int vidx = q * 8000 + i + c;
        const v4f* h4 = (const v4f*)hcache;
        const v4f* w4 = (const v4f*)(Wfc + (size_t)vidx * HID);
        v4f s0 = 0, s1 = 0;
        for (int k = 0; k < 128; k += 2) {
          s0 += h4[k] * w4[k];
          s1 += h4[k + 1] * w4[k + 1];
        }
        v4f sv = s0 + s1;
        float d = bfc[vidx] + sv[0] + sv[1] + sv[2] + sv[3];
        u64 key = ((u64)fenc(d) << 32) | (u64)(0xFFFFFFFFu - (unsigned)vidx);
        atomicMax(&best[b], key);
      }
    }
  }
}

// h_fin epilogue: [2][64][512] appended after logits (final h lives in slot 0)
__global__ void k_hfin(const float* __restrict__ h0buf, const float* __restrict__ h1buf,
                       float* __restrict__ out) {
  int lin = (int)blockIdx.x * 256 + (int)threadIdx.x;
  int l = lin >> 15, r2 = lin & 32767;
  out[65536000 + lin] = (l ? h1buf : h0buf)[r2];
}

extern "C" void kernel_launch(void* const* d_in, const int* in_sizes, int n_in, void* d_out,
                              int out_size, void* d_ws, size_t ws_size, hipStream_t stream) {
  const int* x = (const int*)d_in[0];
  const float* emb = (const float*)d_in[1];
  const float* Wih = (const float*)d_in[2];
  const float* Whh = (const float*)d_in[3];
  const float* bih = (const float*)d_in[4];
  const float* bhh = (const float*)d_in[5];
  const float* Wfc = (const float*)d_in[6];
  const float* bfc = (const float*)d_in[7];
  float* out = (float*)d_out;
  char* ws = (char*)d_ws;

  float* P0 = (float*)ws;                          // [256][64][512] -> becomes H0 in-place
  float* P1 = P0 + (size_t)SEQL * BH;              // [256][64][512]
  unsigned short* Wfcb = (unsigned short*)(P1 + (size_t)SEQL * BH);  // [32000][512] bf16
  char* small = (char*)(Wfcb + (size_t)NV * HID);
  float* h0buf = (float*)small;                    // [2][64][512]
  float* h1buf = h0buf + 2 * BH;                   // [2][64][512]
  unsigned short* h1bf = (unsigned short*)(h1buf + 2 * BH);  // [64][512] bf16
  float* pmaxp = (float*)(h1bf + BH);              // [64 b][256 wg] (b-major)
  u64* best = (u64*)(pmaxp + 256 * 64);            // [64]
  int* flags = (int*)(best + 64);                  // [(256 arrivals + 16 release)*FPAD]
  size_t small_bytes = (size_t)2 * BH * 4 + (size_t)2 * BH * 4 + BH * 2 + 256 * 64 * 4 +
                       64 * 8 + (256 + 16) * FPAD * 4;

  hipMemsetAsync(small, 0, small_bytes, stream);  // h=0, best=0, flags epoch 0
  k_wfcb<<<2048, 256, 0, stream>>>(Wfc, Wfcb);
  // encoder layer0 ih-part: P0 = gather(emb, x) @ Wih0^T + bih0
  k_gemm<1><<<512, 256, 0, stream>>>(nullptr, x, emb, Wih, bih, P0);
  // layer0 scan (stores H0 in-place into P0); final h0 -> h0buf slot 0
  k_scan<<<256, 256, 0, stream>>>(P0, Whh, bhh, h0buf, flags, 1, 0u);
  // layer1 ih-part: P1 = H0 @ Wih1^T + bih1
  k_gemm<0><<<512, 256, 0, stream>>>(P0, nullptr, nullptr, Wih + 262144, bih + 512, P1);
  // layer1 scan; final h1 -> h1buf slot 0
  k_scan<<<256, 256, 0, stream>>>(P1, Whh + 262144, bhh + 512, h1buf, flags, 0, 256u);
  // decoder: 32 steps x 4 stream-ordered phase dispatches (R5)
  for (int st = 0; st < TDEC; st++) {
    k_cell<0><<<256, 256, 0, stream>>>(emb, Wih, Whh, bih, bhh, best, h0buf, h1buf, h1bf, st);
    k_cell<1><<<256, 256, 0, stream>>>(emb, Wih, Whh, bih, bhh, best, h0buf, h1buf, h1bf, st);
    k_logits<<<251, 256, 0, stream>>>(Wfcb, h1bf, bfc, out, pmaxp, best, st);
    k_argmax<<<256, 256, 0, stream>>>(Wfc, bfc, h1buf, pmaxp, out, best, st);
  }
  k_hfin<<<256, 256, 0, stream>>>(h0buf, h1buf, out);
}

// Round 6
// 5635.259 us; speedup vs baseline: 1.3595x; 1.1586x over previous
//
#include <hip/hip_runtime.h>
#include <hip/hip_bf16.h>

// trajectory2seq: 2-layer Elman RNN encoder (SEQ=256) + greedy decoder (32 steps)
// R3: logits Wfcb strip double-buffered through LDS (global_load_lds, counted vmcnt).
// R5: decoder de-persisted into 32 x {cell0, cell1, logits, argmax} stream dispatches
//     (-1.1ms; persistent-kernel exchange machinery was the cost, not poll traffic).
// R6: the two encoder scans (2 x 1677us, 51% of total) PIPELINED into one 512-wg
// kernel. Layer-1 step t only needs layer-0's h0[t] (lag-1 dependence). wgs 0-255:
// layer0 as before, h0 -> 4-slot ring. wgs 256-511: layer1, computes ih1 matvec
// on the fly from h0[t] (k_gemm<0> and P1 eliminated) + hh1 from h1[t-1]; the hh1
// compute overlaps the wait for h0[t]. Back-pressure: layer0 master also waits
// layer1 release >= ep-3 (4-slot ring => no steady-state stall, lag ~1 step).
// 512 wgs co-resident at 2 wgs/CU (33.8KB LDS, launch_bounds(256,2)).

typedef float v4f __attribute__((ext_vector_type(4)));
typedef short short8 __attribute__((ext_vector_type(8)));
typedef unsigned long long u64;

#define HID 512
#define NBAT 64
#define SEQL 256
#define NV 32000
#define TDEC 32
#define BH (64 * 512)
#define FPAD 32  // flags padded to 128B lines

__device__ __forceinline__ unsigned short f2bf(float f) {
  unsigned u = __float_as_uint(f);
  u = u + 0x7FFFu + ((u >> 16) & 1u);  // RNE
  return (unsigned short)(u >> 16);
}
__device__ __forceinline__ unsigned fenc(float f) {
  unsigned u = __float_as_uint(f);
  return (u & 0x80000000u) ? ~u : (u | 0x80000000u);
}
// device-scope relaxed atomics (scan-internal cross-wg h exchange only)
__device__ __forceinline__ float ldf(const float* p) {
  return __hip_atomic_load(p, __ATOMIC_RELAXED, __HIP_MEMORY_SCOPE_AGENT);
}
__device__ __forceinline__ void stf(float* p, float v) {
  __hip_atomic_store(p, v, __ATOMIC_RELAXED, __HIP_MEMORY_SCOPE_AGENT);
}
__device__ __forceinline__ int ldflag(const int* p) {
  return __hip_atomic_load(p, __ATOMIC_RELAXED, __HIP_MEMORY_SCOPE_AGENT);
}
__device__ __forceinline__ void stflag(int* p, int v) {
  __hip_atomic_store(p, v, __ATOMIC_RELAXED, __HIP_MEMORY_SCOPE_AGENT);
}

// ---------------- W_fc fp32 -> bf16 ----------------
__global__ void k_wfcb(const float* __restrict__ W, unsigned short* __restrict__ Wb) {
  const int n = NV * HID;
  for (int i = ((int)blockIdx.x * 256 + (int)threadIdx.x) * 8; i < n; i += 2048 * 256 * 8) {
    v4f a = *(const v4f*)(W + i);
    v4f b = *(const v4f*)(W + i + 4);
    short8 o;
    o[0] = (short)f2bf(a[0]); o[1] = (short)f2bf(a[1]);
    o[2] = (short)f2bf(a[2]); o[3] = (short)f2bf(a[3]);
    o[4] = (short)f2bf(b[0]); o[5] = (short)f2bf(b[1]);
    o[6] = (short)f2bf(b[2]); o[7] = (short)f2bf(b[3]);
    *(short8*)(Wb + i) = o;
  }
}

// ---------------- fp32 GEMM: P[i][j] = sum_k A[i][k]*W[j][k] + bias[j] ----------------
template <int GATHER>
__global__ __launch_bounds__(256, 2) void k_gemm(const float* __restrict__ A,
                                                 const int* __restrict__ xtok,
                                                 const float* __restrict__ emb,
                                                 const float* __restrict__ W,
                                                 const float* __restrict__ bias,
                                                 float* __restrict__ P) {
  __shared__ __align__(16) float As[32 * 132];
  __shared__ __align__(16) float Bs[32 * 132];
  const int tid = threadIdx.x;
  const int i0 = ((int)blockIdx.x >> 2) * 128, j0 = ((int)blockIdx.x & 3) * 128;
  const int tx = tid & 15, ty = tid >> 4;
  float acc[8][8] = {};
  const int sa = 4 * ((tx >> 2) & 1);
  const int sb = 4 * ((ty >> 2) & 1);
  const int pa0 = (tx * 8) ^ sa, pa1 = (tx * 8 + 4) ^ sa;
  const int pb0 = (ty * 8) ^ sb, pb1 = (ty * 8 + 4) ^ sb;
  for (int kc = 0; kc < HID; kc += 32) {
#pragma unroll
    for (int u = 0; u < 4; u++) {
      int lin = tid + u * 256;
      int il = lin >> 3, kq = (lin & 7) * 4;
      int pi = il ^ (4 * ((il >> 5) & 1));
      const float* asrc;
      if (GATHER) {
        int row = i0 + il;
        int tok = xtok[(row & 63) * SEQL + (row >> 6)];  // x[b][t], row = t*64+b
        asrc = emb + (size_t)tok * HID + kc + kq;
      } else {
        asrc = A + (size_t)(i0 + il) * HID + kc + kq;
      }
      v4f av = *(const v4f*)asrc;
      v4f bv = *(const v4f*)(W + (size_t)(j0 + il) * HID + kc + kq);
      As[(kq + 0) * 132 + pi] = av[0]; As[(kq + 1) * 132 + pi] = av[1];
      As[(kq + 2) * 132 + pi] = av[2]; As[(kq + 3) * 132 + pi] = av[3];
      Bs[(kq + 0) * 132 + pi] = bv[0]; Bs[(kq + 1) * 132 + pi] = bv[1];
      Bs[(kq + 2) * 132 + pi] = bv[2]; Bs[(kq + 3) * 132 + pi] = bv[3];
    }
    __syncthreads();
#pragma unroll 8
    for (int k = 0; k < 32; k++) {
      v4f a0 = *(const v4f*)&As[k * 132 + pa0];
      v4f a1 = *(const v4f*)&As[k * 132 + pa1];
      v4f b0 = *(const v4f*)&Bs[k * 132 + pb0];
      v4f b1 = *(const v4f*)&Bs[k * 132 + pb1];
      float ar[8] = {a0[0], a0[1], a0[2], a0[3], a1[0], a1[1], a1[2], a1[3]};
      float br[8] = {b0[0], b0[1], b0[2], b0[3], b1[0], b1[1], b1[2], b1[3]};
#pragma unroll
      for (int r = 0; r < 8; r++)
#pragma unroll
        for (int c = 0; c < 8; c++) acc[r][c] = fmaf(ar[r], br[c], acc[r][c]);
    }
    __syncthreads();
  }
  v4f bl0 = *(const v4f*)(bias + j0 + ty * 8);
  v4f bl1 = *(const v4f*)(bias + j0 + ty * 8 + 4);
#pragma unroll
  for (int r = 0; r < 8; r++) {
    float* dst = P + (size_t)(i0 + tx * 8 + r) * HID + j0 + ty * 8;
    v4f o0 = {acc[r][0] + bl0[0], acc[r][1] + bl0[1], acc[r][2] + bl0[2], acc[r][3] + bl0[3]};
    v4f o1 = {acc[r][4] + bl1[0], acc[r][5] + bl1[1], acc[r][6] + bl1[2], acc[r][7] + bl1[3]};
    *(v4f*)dst = o0;
    *(v4f*)(dst + 4) = o1;
  }
}

// ---------------- R6: pipelined 2-layer recurrence scan ----------------
// 512 wgs. wgs 0-255: layer0 (8 bgroups x 32 jgroups, Whh0 slice in VGPRs), h0 into
// 4-slot ring. wgs 256-511: layer1 (Whh1+Wih1 slices in VGPRs), lag-1 behind layer0:
// per step t, compute Whh1*h1[t-1] while layer0 finishes h0[t], then Wih1*h0[t].
// Flags: arrivals[wgid] 0..511; releases A[g]=512+g (layer0), B[g]=520+g (layer1).
__global__ __launch_bounds__(256, 2) void k_scan2(
    const float* __restrict__ P0, const float* __restrict__ Wih,
    const float* __restrict__ Whh, const float* __restrict__ bih,
    const float* __restrict__ bhh, float* __restrict__ h0ring,
    float* __restrict__ h0buf, float* __restrict__ h1buf, int* __restrict__ flags) {
  __shared__ __align__(16) float hs0[32 * 132];
  __shared__ __align__(16) float hs1[32 * 132];
  const int wgid = blockIdx.x, tid = threadIdx.x;
  const int layer = wgid >> 8;
  const int wg = wgid & 255;
  const int bg = wg >> 5, jg = wg & 31;
  const int b0 = bg * 8, j0 = jg * 16;
  const int bh = tid & 1, jg2 = (tid >> 1) & 3, ks = tid >> 3;
  int* arr = &flags[wgid * FPAD];
  int* relA = &flags[(512 + bg) * FPAD];
  int* relB = &flags[(520 + bg) * FPAD];

  if (layer == 0) {
    v4f wv[4][4];
#pragma unroll
    for (int jj = 0; jj < 4; jj++)
#pragma unroll
      for (int i4 = 0; i4 < 4; i4++)
        wv[jj][i4] = *(const v4f*)(Whh + (size_t)(j0 + jg2 * 4 + jj) * HID + ks * 16 + i4 * 4);
    for (int t = 0; t < SEQL; t++) {
      const float* hsrc = h0ring + ((t + 3) & 3) * BH + b0 * HID;  // h0[t-1]; slot3 zeroed
#pragma unroll
      for (int u = 0; u < 16; u++) {
        int lin = tid + u * 256;
        int b = lin >> 9, k = lin & 511;
        hs0[(k >> 4) * 132 + b * 16 + (k & 15)] = ldf(hsrc + b * HID + k);
      }
      __syncthreads();
      float acc[4][4] = {};
#pragma unroll
      for (int i4 = 0; i4 < 4; i4++) {
#pragma unroll
        for (int bb = 0; bb < 4; bb++) {
          int b = bh * 4 + bb;
          v4f hv = *(const v4f*)&hs0[ks * 132 + b * 16 + i4 * 4];
#pragma unroll
          for (int jj = 0; jj < 4; jj++) {
            float a = acc[bb][jj];
            a = fmaf(hv[0], wv[jj][i4][0], a);
            a = fmaf(hv[1], wv[jj][i4][1], a);
            a = fmaf(hv[2], wv[jj][i4][2], a);
            a = fmaf(hv[3], wv[jj][i4][3], a);
            acc[bb][jj] = a;
          }
        }
      }
      __syncthreads();  // reuse hs0 as partials [ks32][b8][j16]
#pragma unroll
      for (int bb = 0; bb < 4; bb++) {
        v4f pv = {acc[bb][0], acc[bb][1], acc[bb][2], acc[bb][3]};
        *(v4f*)&hs0[ks * 132 + (bh * 4 + bb) * 16 + jg2 * 4] = pv;
      }
      __syncthreads();
      if (tid < 128) {
        int bb = tid >> 4, jj = tid & 15;
        float sum = 0.f;
#pragma unroll
        for (int k2 = 0; k2 < 32; k2++) sum += hs0[k2 * 132 + bb * 16 + jj];
        int jglob = j0 + jj, bglob = b0 + bb;
        float z = P0[(size_t)t * BH + bglob * HID + jglob] + bhh[jglob] + sum;
        float h = tanhf(z);
        stf(&h0ring[(t & 3) * BH + bglob * HID + jglob], h);
        if (t == SEQL - 1) stf(&h0buf[bglob * HID + jglob], h);  // decoder h0 seed (slot 0)
      }
      // barrier (group of 32) + back-pressure on layer1 (ring depth 4)
      unsigned ep = (unsigned)(t + 1);
      __atomic_signal_fence(__ATOMIC_SEQ_CST);
      __builtin_amdgcn_s_waitcnt(0);
      __syncthreads();
      if (tid == 0) stflag(arr, (int)ep);
      if (jg == 0) {
        if (tid < 32) {
          while ((unsigned)ldflag(&flags[(bg * 32 + tid) * FPAD]) < ep)
            __builtin_amdgcn_s_sleep(1);
        } else if (tid == 32 && ep > 3) {
          while ((unsigned)ldflag(relB) < ep - 3) __builtin_amdgcn_s_sleep(1);
        }
        __syncthreads();
        if (tid == 0) stflag(relA, (int)ep);
      } else if (tid == 0) {
        while ((unsigned)ldflag(relA) < ep) __builtin_amdgcn_s_sleep(2);
      }
      __atomic_signal_fence(__ATOMIC_SEQ_CST);
      __syncthreads();
    }
  } else {
    v4f wvh[4][4], wvi[4][4];
#pragma unroll
    for (int jj = 0; jj < 4; jj++)
#pragma unroll
      for (int i4 = 0; i4 < 4; i4++) {
        size_t off = (size_t)(j0 + jg2 * 4 + jj) * HID + ks * 16 + i4 * 4;
        wvh[jj][i4] = *(const v4f*)(Whh + 262144 + off);
        wvi[jj][i4] = *(const v4f*)(Wih + 262144 + off);
      }
    for (int t = 0; t < SEQL; t++) {
      const int p1 = t & 1;
      // stage h1[t-1] (own-group data from previous barrier; slot 0 zeroed at t=0)
      const float* h1src = h1buf + p1 * BH + b0 * HID;
#pragma unroll
      for (int u = 0; u < 16; u++) {
        int lin = tid + u * 256;
        int b = lin >> 9, k = lin & 511;
        hs1[(k >> 4) * 132 + b * 16 + (k & 15)] = ldf(h1src + b * HID + k);
      }
      __syncthreads();
      float acc[4][4] = {};
#pragma unroll
      for (int i4 = 0; i4 < 4; i4++) {  // hh1 part overlaps the wait for h0[t]
#pragma unroll
        for (int bb = 0; bb < 4; bb++) {
          int b = bh * 4 + bb;
          v4f hv = *(const v4f*)&hs1[ks * 132 + b * 16 + i4 * 4];
#pragma unroll
          for (int jj = 0; jj < 4; jj++) {
            float a = acc[bb][jj];
            a = fmaf(hv[0], wvh[jj][i4][0], a);
            a = fmaf(hv[1], wvh[jj][i4][1], a);
            a = fmaf(hv[2], wvh[jj][i4][2], a);
            a = fmaf(hv[3], wvh[jj][i4][3], a);
            acc[bb][jj] = a;
          }
        }
      }
      // wait for layer0's h0[t]
      if (tid == 0) {
        while ((unsigned)ldflag(relA) < (unsigned)(t + 1)) __builtin_amdgcn_s_sleep(2);
      }
      __atomic_signal_fence(__ATOMIC_SEQ_CST);
      __syncthreads();
      const float* h0src = h0ring + (t & 3) * BH + b0 * HID;
#pragma unroll
      for (int u = 0; u < 16; u++) {
        int lin = tid + u * 256;
        int b = lin >> 9, k = lin & 511;
        hs0[(k >> 4) * 132 + b * 16 + (k & 15)] = ldf(h0src + b * HID + k);
      }
      __syncthreads();
#pragma unroll
      for (int i4 = 0; i4 < 4; i4++) {  // ih1 part
#pragma unroll
        for (int bb = 0; bb < 4; bb++) {
          int b = bh * 4 + bb;
          v4f hv = *(const v4f*)&hs0[ks * 132 + b * 16 + i4 * 4];
#pragma unroll
          for (int jj = 0; jj < 4; jj++) {
            float a = acc[bb][jj];
            a = fmaf(hv[0], wvi[jj][i4][0], a);
            a = fmaf(hv[1], wvi[jj][i4][1], a);
            a = fmaf(hv[2], wvi[jj][i4][2], a);
            a = fmaf(hv[3], wvi[jj][i4][3], a);
            acc[bb][jj] = a;
          }
        }
      }
      __syncthreads();  // reuse hs1 as partials
#pragma unroll
      for (int bb = 0; bb < 4; bb++) {
        v4f pv = {acc[bb][0], acc[bb][1], acc[bb][2], acc[bb][3]};
        *(v4f*)&hs1[ks * 132 + (bh * 4 + bb) * 16 + jg2 * 4] = pv;
      }
      __syncthreads();
      if (tid < 128) {
        int bb = tid >> 4, jj = tid & 15;
        float sum = 0.f;
#pragma unroll
        for (int k2 = 0; k2 < 32; k2++) sum += hs1[k2 * 132 + bb * 16 + jj];
        int jglob = j0 + jj, bglob = b0 + bb;
        float z = bih[HID + jglob] + bhh[HID + jglob] + sum;
        float h = tanhf(z);
        stf(&h1buf[(p1 ^ 1) * BH + bglob * HID + jglob], h);  // t=255 -> slot 0 (decoder seed)
      }
      // own-group barrier
      unsigned ep = (unsigned)(t + 1);
      __atomic_signal_fence(__ATOMIC_SEQ_CST);
      __builtin_amdgcn_s_waitcnt(0);
      __syncthreads();
      if (tid == 0) stflag(arr, (int)ep);
      if (jg == 0) {
        if (tid < 32) {
          while ((unsigned)ldflag(&flags[(256 + bg * 32 + tid) * FPAD]) < ep)
            __builtin_amdgcn_s_sleep(1);
        }
        __syncthreads();
        if (tid == 0) stflag(relB, (int)ep);
      } else if (tid == 0) {
        while ((unsigned)ldflag(relB) < ep) __builtin_amdgcn_s_sleep(2);
      }
      __atomic_signal_fence(__ATOMIC_SEQ_CST);
      __syncthreads();
    }
  }
}

// issue one 32KB Wfcb k-tile (128 cols x 128 k, bf16) into LDS via global_load_lds.
__device__ __forceinline__ void issue_tile(const unsigned short* __restrict__ Wfcb,
                                           float* buf, int wg, int tid, int T) {
  const int wv = tid >> 6, ln = tid & 63;
  const unsigned short* sb =
      Wfcb + (size_t)(wg * 128 + wv * 32 + (ln & 15)) * HID + T * 128 + (ln >> 4) * 8;
#pragma unroll
  for (int kc = 0; kc < 4; kc++)
#pragma unroll
    for (int fq = 0; fq < 2; fq++)
      __builtin_amdgcn_global_load_lds(
          (const unsigned int*)(sb + (size_t)fq * 16 * HID + kc * 32),
          (unsigned int*)(buf + wv * 2048 + kc * 512 + fq * 256), 16, 0, 0);
}

// ---------------- decoder phase kernels (R5: one dispatch per phase) ----------------
template <int PH>
__global__ __launch_bounds__(256, 1) void k_cell(
    const float* __restrict__ emb, const float* __restrict__ Wih,
    const float* __restrict__ Whh, const float* __restrict__ bih,
    const float* __restrict__ bhh, const u64* __restrict__ best,
    float* __restrict__ h0buf, float* __restrict__ h1buf,
    unsigned short* __restrict__ h1bf, int st) {
  __shared__ __align__(16) float Wl[2 * 4224];   // [ih,hh][ks32][j8][k16]+pad
  __shared__ __align__(16) float es[32 * 268];   // input stage / partials
  __shared__ __align__(16) float hss[32 * 268];  // h stage
  const int wg = blockIdx.x, tid = threadIdx.x;
  const int bg = wg >> 6, jgD = wg & 63;
  const int bh = tid & 3, jg2 = (tid >> 2) & 1, ks = tid >> 3;
  const int p = st & 1;
#pragma unroll
  for (int m = 0; m < 2; m++) {
    const float* src = (m ? Whh : Wih) + (size_t)PH * HID * HID;
#pragma unroll
    for (int u = 0; u < 4; u++) {
      int lin = tid + u * 256;
      int j = lin >> 7, k4 = (lin & 127) * 4;
      v4f v = *(const v4f*)(src + (size_t)(jgD * 8 + j) * HID + k4);
      *(v4f*)&Wl[m * 4224 + (k4 >> 4) * 132 + j * 16 + (k4 & 15)] = v;
    }
  }
  if (PH == 0) {
#pragma unroll
    for (int u = 0; u < 8; u++) {
      int lin = tid + u * 256;
      int b = lin >> 7, k4 = (lin & 127) * 4;
      unsigned vtok = 0u;
      if (st > 0) {
        u64 kk = best[bg * 16 + b];
        vtok = 0xFFFFFFFFu - (unsigned)(kk & 0xFFFFFFFFull);
        if (vtok >= (unsigned)NV) vtok = 0u;
      }
      v4f av = *(const v4f*)(emb + (size_t)vtok * HID + k4);
      *(v4f*)&es[(k4 >> 4) * 268 + b * 16 + (k4 & 15)] = av;
    }
#pragma unroll
    for (int u = 0; u < 32; u++) {
      int lin = tid + u * 256;
      int b = lin >> 9, k = lin & 511;
      hss[(k >> 4) * 268 + b * 16 + (k & 15)] = h0buf[p * BH + (bg * 16 + b) * HID + k];
    }
  } else {
#pragma unroll
    for (int u = 0; u < 32; u++) {
      int lin = tid + u * 256;
      int b = lin >> 9, k = lin & 511;
      int off = (k >> 4) * 268 + b * 16 + (k & 15);
      int row = (bg * 16 + b) * HID + k;
      es[off] = h0buf[(p ^ 1) * BH + row];
      hss[off] = h1buf[p * BH + row];
    }
  }
  __syncthreads();
  float acc[4][4] = {};
  const float* Wi = &Wl[0];
  const float* Wh = &Wl[4224];
#pragma unroll
  for (int i4 = 0; i4 < 4; i4++) {
    v4f wi[4], wh[4];
#pragma unroll
    for (int jj = 0; jj < 4; jj++) {
      wi[jj] = *(const v4f*)&Wi[ks * 132 + (jg2 * 4 + jj) * 16 + i4 * 4];
      wh[jj] = *(const v4f*)&Wh[ks * 132 + (jg2 * 4 + jj) * 16 + i4 * 4];
    }
#pragma unroll
    for (int bb = 0; bb < 4; bb++) {
      int b = bh * 4 + bb;
      v4f evv = *(const v4f*)&es[ks * 268 + b * 16 + i4 * 4];
      v4f hvv = *(const v4f*)&hss[ks * 268 + b * 16 + i4 * 4];
#pragma unroll
      for (int jj = 0; jj < 4; jj++) {
        float a = acc[bb][jj];
        a = fmaf(evv[0], wi[jj][0], a); a = fmaf(evv[1], wi[jj][1], a);
        a = fmaf(evv[2], wi[jj][2], a); a = fmaf(evv[3], wi[jj][3], a);
        a = fmaf(hvv[0], wh[jj][0], a); a = fmaf(hvv[1], wh[jj][1], a);
        a = fmaf(hvv[2], wh[jj][2], a); a = fmaf(hvv[3], wh[jj][3], a);
        acc[bb][jj] = a;
      }
    }
  }
  __syncthreads();  // partials alias es: [ks32][b16][j8]
#pragma unroll
  for (int bb = 0; bb < 4; bb++) {
    v4f pv = {acc[bb][0], acc[bb][1], acc[bb][2], acc[bb][3]};
    *(v4f*)&es[ks * 132 + (bh * 4 + bb) * 8 + jg2 * 4] = pv;
  }
  __syncthreads();
  if (tid < 128) {
    int b = tid >> 3, j = tid & 7;
    float sum = 0.f;
#pragma unroll
    for (int k2 = 0; k2 < 32; k2++) sum += es[k2 * 132 + b * 8 + j];
    int jglob = jgD * 8 + j, bglob = bg * 16 + b;
    float z = bih[PH * HID + jglob] + bhh[PH * HID + jglob] + sum;
    float h = tanhf(z);
    float* hb = (PH ? h1buf : h0buf);
    hb[(p ^ 1) * BH + bglob * HID + jglob] = h;
    if (PH) {  // pack bf16 pairs, even-j lanes store 4B
      unsigned hbv = f2bf(h);
      unsigned nb = (unsigned)__shfl_down((int)hbv, 1);
      if ((j & 1) == 0)
        *(unsigned*)(h1bf + (size_t)bglob * HID + jglob) = hbv | (nb << 16);
    }
  }
}

// logits = h1 @ Wfc^T + bfc (bf16 MFMA, Wfcb via LDS double-buffer) + per-wg col max.
__global__ __launch_bounds__(256, 1) void k_logits(
    const unsigned short* __restrict__ Wfcb, const unsigned short* __restrict__ h1bf,
    const float* __restrict__ bfc, float* __restrict__ out, float* __restrict__ pmaxp,
    u64* __restrict__ best, int st) {
  __shared__ __align__(16) float tb0[8192];
  __shared__ __align__(16) float tb1[8192];
  __shared__ float pmr[256];
  const int wg = blockIdx.x, tid = threadIdx.x;
  if (wg == 250) {
    if (tid < 64) best[tid] = 0ull;
    return;
  }
  const int w = tid >> 6, lane = tid & 63;
  const int l16 = lane & 15, quad = lane >> 4;
  const int n0 = wg * 128 + w * 32;
  const int nc0 = n0 + l16, nc1 = n0 + 16 + l16;
  const float bf0 = bfc[nc0], bf1 = bfc[nc1];
  issue_tile(Wfcb, tb0, wg, tid, 0);
  v4f acc[4][2] = {};
#pragma unroll
  for (int t = 0; t < 4; t++) {
    __builtin_amdgcn_sched_barrier(0);
    const float* buf = (t & 1) ? tb1 : tb0;
    union { u64 q[2]; short8 s; } au[4][4];
#pragma unroll
    for (int mb = 0; mb < 4; mb++) {
      const unsigned short* hr = h1bf + (size_t)(mb * 16 + l16) * HID + t * 128 + quad * 8;
#pragma unroll
      for (int kc = 0; kc < 4; kc++) {
        au[mb][kc].q[0] = *(const u64*)(hr + kc * 32);
        au[mb][kc].q[1] = *(const u64*)(hr + kc * 32 + 4);
      }
    }
    __builtin_amdgcn_sched_barrier(0);
    if (t < 3) issue_tile(Wfcb, (t & 1) ? tb0 : tb1, wg, tid, t + 1);
    __builtin_amdgcn_sched_barrier(0);
    if (t < 3) asm volatile("s_waitcnt vmcnt(8)" ::: "memory");
    else       asm volatile("s_waitcnt vmcnt(0)" ::: "memory");
    __builtin_amdgcn_sched_barrier(0);
#pragma unroll
    for (int kc = 0; kc < 4; kc++) {
      short8 b0 = *(const short8*)(buf + w * 2048 + kc * 512 + lane * 4);
      short8 b1 = *(const short8*)(buf + w * 2048 + kc * 512 + 256 + lane * 4);
#pragma unroll
      for (int mb = 0; mb < 4; mb++) {
        acc[mb][0] =
            __builtin_amdgcn_mfma_f32_16x16x32_bf16(au[mb][kc].s, b0, acc[mb][0], 0, 0, 0);
        acc[mb][1] =
            __builtin_amdgcn_mfma_f32_16x16x32_bf16(au[mb][kc].s, b1, acc[mb][1], 0, 0, 0);
      }
    }
  }
#pragma unroll
  for (int mb = 0; mb < 4; mb++) {
#pragma unroll
    for (int r = 0; r < 4; r++) {
      float v0 = acc[mb][0][r] + bf0;
      float v1 = acc[mb][1][r] + bf1;
      int m = mb * 16 + quad * 4 + r;  // C/D: col=lane&15, row=quad*4+reg
      out[(size_t)(m * TDEC + st) * NV + nc0] = v0;
      out[(size_t)(m * TDEC + st) * NV + nc1] = v1;
      float mx = fmaxf(v0, v1);
      mx = fmaxf(mx, __shfl_xor(mx, 1));
      mx = fmaxf(mx, __shfl_xor(mx, 2));
      mx = fmaxf(mx, __shfl_xor(mx, 4));
      mx = fmaxf(mx, __shfl_xor(mx, 8));
      if (l16 == 0) pmr[w * 64 + m] = mx;
    }
  }
  __syncthreads();
  if (tid < 64) {
    float m4 = fmaxf(fmaxf(pmr[tid], pmr[64 + tid]), fmaxf(pmr[128 + tid], pmr[192 + tid]));
    pmaxp[tid * 256 + wg] = m4;  // b-major: argmax reads 250 contiguous floats
  }
}

// candidate refine + argmax. grid 256: wg = b*4 + quarter (8000 vocab each).
__global__ __launch_bounds__(256, 1) void k_argmax(
    const float* __restrict__ Wfc, const float* __restrict__ bfc,
    const float* __restrict__ h1buf, const float* __restrict__ pmaxp,
    const float* __restrict__ out, u64* __restrict__ best, int st) {
  __shared__ __align__(16) float hcache[512];
  __shared__ float red[256];
  const int wg = blockIdx.x, tid = threadIdx.x;
  const int b = wg >> 2, q = wg & 3;
  const int p = st & 1;
  const float* hrow = h1buf + (p ^ 1) * BH + b * HID;
  hcache[tid] = hrow[tid];
  hcache[tid + 256] = hrow[tid + 256];
  red[tid] = (tid < 250) ? pmaxp[b * 256 + tid] : -3.0e38f;
  __syncthreads();
  for (int o = 128; o > 0; o >>= 1) {
    if (tid < o) red[tid] = fmaxf(red[tid], red[tid + o]);
    __syncthreads();
  }
  const float thr = red[0] - 0.05f;
  const size_t ob = (size_t)(b * TDEC + st) * NV + q * 8000;
  for (int i = tid * 2; i < 8000; i += 512) {
    u64 qq = *(const u64*)(out + ob + i);
    float lv[2] = {__uint_as_float((unsigned)qq), __uint_as_float((unsigned)(qq >> 32))};
#pragma unroll
    for (int c = 0; c < 2; c++) {
      if (lv[c] >= thr) {
        int vidx = q * 8000 + i + c;
        const v4f* h4 = (const v4f*)hcache;
        const v4f* w4 = (const v4f*)(Wfc + (size_t)vidx * HID);
        v4f s0 = 0, s1 = 0;
        for (int k = 0; k < 128; k += 2) {
          s0 += h4[k] * w4[k];
          s1 += h4[k + 1] * w4[k + 1];
        }
        v4f sv = s0 + s1;
        float d = bfc[vidx] + sv[0] + sv[1] + sv[2] + sv[3];
        u64 key = ((u64)fenc(d) << 32) | (u64)(0xFFFFFFFFu - (unsigned)vidx);
        atomicMax(&best[b], key);
      }
    }
  }
}

// h_fin epilogue: [2][64][512] appended after logits (final h lives in slot 0)
__global__ void k_hfin(const float* __restrict__ h0buf, const float* __restrict__ h1buf,
                       float* __restrict__ out) {
  int lin = (int)blockIdx.x * 256 + (int)threadIdx.x;
  int l = lin >> 15, r2 = lin & 32767;
  out[65536000 + lin] = (l ? h1buf : h0buf)[r2];
}

extern "C" void kernel_launch(void* const* d_in, const int* in_sizes, int n_in, void* d_out,
                              int out_size, void* d_ws, size_t ws_size, hipStream_t stream) {
  const int* x = (const int*)d_in[0];
  const float* emb = (const float*)d_in[1];
  const float* Wih = (const float*)d_in[2];
  const float* Whh = (const float*)d_in[3];
  const float* bih = (const float*)d_in[4];
  const float* bhh = (const float*)d_in[5];
  const float* Wfc = (const float*)d_in[6];
  const float* bfc = (const float*)d_in[7];
  float* out = (float*)d_out;
  char* ws = (char*)d_ws;

  float* P0 = (float*)ws;                          // [256][64][512]
  float* P1space = P0 + (size_t)SEQL * BH;         // old P1 region; h0ring lives here
  float* h0ring = P1space;                         // [4][64][512] ring (R6)
  unsigned short* Wfcb = (unsigned short*)(P1space + (size_t)SEQL * BH);  // [32000][512] bf16
  char* small = (char*)(Wfcb + (size_t)NV * HID);
  float* h0buf = (float*)small;                    // [2][64][512] (decoder state)
  float* h1buf = h0buf + 2 * BH;                   // [2][64][512]
  unsigned short* h1bf = (unsigned short*)(h1buf + 2 * BH);  // [64][512] bf16
  float* pmaxp = (float*)(h1bf + BH);              // [64 b][256 wg] (b-major)
  u64* best = (u64*)(pmaxp + 256 * 64);            // [64]
  int* flags = (int*)(best + 64);                  // [(512 arrivals + 16 releases)*FPAD]
  size_t small_bytes = (size_t)2 * BH * 4 + (size_t)2 * BH * 4 + BH * 2 + 256 * 64 * 4 +
                       64 * 8 + (512 + 16) * FPAD * 4;

  hipMemsetAsync(small, 0, small_bytes, stream);       // h=0, best=0, flags epoch 0
  hipMemsetAsync(h0ring, 0, (size_t)4 * BH * 4, stream);  // ring slot 3 = h0[-1] = 0
  k_wfcb<<<2048, 256, 0, stream>>>(Wfc, Wfcb);
  // encoder layer0 ih-part: P0 = gather(emb, x) @ Wih0^T + bih0
  k_gemm<1><<<512, 256, 0, stream>>>(nullptr, x, emb, Wih, bih, P0);
  // R6: pipelined 2-layer scan (ih1 computed on the fly; P1/gemm<0> eliminated)
  k_scan2<<<512, 256, 0, stream>>>(P0, Wih, Whh, bih, bhh, h0ring, h0buf, h1buf, flags);
  // decoder: 32 steps x 4 stream-ordered phase dispatches (R5)
  for (int st = 0; st < TDEC; st++) {
    k_cell<0><<<256, 256, 0, stream>>>(emb, Wih, Whh, bih, bhh, best, h0buf, h1buf, h1bf, st);
    k_cell<1><<<256, 256, 0, stream>>>(emb, Wih, Whh, bih, bhh, best, h0buf, h1buf, h1bf, st);
    k_logits<<<251, 256, 0, stream>>>(Wfcb, h1bf, bfc, out, pmaxp, best, st);
    k_argmax<<<256, 256, 0, stream>>>(Wfc, bfc, h1buf, pmaxp, out, best, st);
  }
  k_hfin<<<256, 256, 0, stream>>>(h0buf, h1buf, out);
}

// Round 7
// 5509.928 us; speedup vs baseline: 1.3904x; 1.0227x over previous
//
#include <hip/hip_runtime.h>
#include <hip/hip_bf16.h>

// trajectory2seq: 2-layer Elman RNN encoder (SEQ=256) + greedy decoder (32 steps)
// R3: logits Wfcb strip double-buffered through LDS (global_load_lds, counted vmcnt).
// R5: decoder de-persisted into 32 x {cell0, cell1, logits, argmax} stream dispatches.
// R6: encoder scans pipelined into one 512-wg kernel (layer1 lag-1 behind layer0,
//     ih1 computed on the fly; k_gemm<0>/P1 eliminated). 6529 -> 5635us.
// R7: scan sync FLATTENED. R4 proved poll-traffic volume is irrelevant (flat ==
// hierarchical on the decoder), so the master/release hierarchy only costs 2 extra
// serialized LLC hops per sync (master-detect + release-publish). Now every sync
// point polls the 32 producer arrival flags directly (one lane per flag):
//  - L0 end-of-step: tid<32 poll own-bg L0 arrivals; tid 32..63 poll L1 arrivals
//    >= ep-3 (ring backpressure, flattened).
//  - L1 mid-step: tid<32 poll L0 arrivals >= t+1 (was relA).
//  - L1 end-of-step: tid<32 poll own-bg L1 arrivals.
// Also: P0[t] slice prefetched into a register at step start. Numerics unchanged.

typedef float v4f __attribute__((ext_vector_type(4)));
typedef short short8 __attribute__((ext_vector_type(8)));
typedef unsigned long long u64;

#define HID 512
#define NBAT 64
#define SEQL 256
#define NV 32000
#define TDEC 32
#define BH (64 * 512)
#define FPAD 32  // flags padded to 128B lines

__device__ __forceinline__ unsigned short f2bf(float f) {
  unsigned u = __float_as_uint(f);
  u = u + 0x7FFFu + ((u >> 16) & 1u);  // RNE
  return (unsigned short)(u >> 16);
}
__device__ __forceinline__ unsigned fenc(float f) {
  unsigned u = __float_as_uint(f);
  return (u & 0x80000000u) ? ~u : (u | 0x80000000u);
}
// device-scope relaxed atomics (scan-internal cross-wg h exchange only)
__device__ __forceinline__ float ldf(const float* p) {
  return __hip_atomic_load(p, __ATOMIC_RELAXED, __HIP_MEMORY_SCOPE_AGENT);
}
__device__ __forceinline__ void stf(float* p, float v) {
  __hip_atomic_store(p, v, __ATOMIC_RELAXED, __HIP_MEMORY_SCOPE_AGENT);
}
__device__ __forceinline__ int ldflag(const int* p) {
  return __hip_atomic_load(p, __ATOMIC_RELAXED, __HIP_MEMORY_SCOPE_AGENT);
}
__device__ __forceinline__ void stflag(int* p, int v) {
  __hip_atomic_store(p, v, __ATOMIC_RELAXED, __HIP_MEMORY_SCOPE_AGENT);
}

// ---------------- W_fc fp32 -> bf16 ----------------
__global__ void k_wfcb(const float* __restrict__ W, unsigned short* __restrict__ Wb) {
  const int n = NV * HID;
  for (int i = ((int)blockIdx.x * 256 + (int)threadIdx.x) * 8; i < n; i += 2048 * 256 * 8) {
    v4f a = *(const v4f*)(W + i);
    v4f b = *(const v4f*)(W + i + 4);
    short8 o;
    o[0] = (short)f2bf(a[0]); o[1] = (short)f2bf(a[1]);
    o[2] = (short)f2bf(a[2]); o[3] = (short)f2bf(a[3]);
    o[4] = (short)f2bf(b[0]); o[5] = (short)f2bf(b[1]);
    o[6] = (short)f2bf(b[2]); o[7] = (short)f2bf(b[3]);
    *(short8*)(Wb + i) = o;
  }
}

// ---------------- fp32 GEMM: P[i][j] = sum_k A[i][k]*W[j][k] + bias[j] ----------------
template <int GATHER>
__global__ __launch_bounds__(256, 2) void k_gemm(const float* __restrict__ A,
                                                 const int* __restrict__ xtok,
                                                 const float* __restrict__ emb,
                                                 const float* __restrict__ W,
                                                 const float* __restrict__ bias,
                                                 float* __restrict__ P) {
  __shared__ __align__(16) float As[32 * 132];
  __shared__ __align__(16) float Bs[32 * 132];
  const int tid = threadIdx.x;
  const int i0 = ((int)blockIdx.x >> 2) * 128, j0 = ((int)blockIdx.x & 3) * 128;
  const int tx = tid & 15, ty = tid >> 4;
  float acc[8][8] = {};
  const int sa = 4 * ((tx >> 2) & 1);
  const int sb = 4 * ((ty >> 2) & 1);
  const int pa0 = (tx * 8) ^ sa, pa1 = (tx * 8 + 4) ^ sa;
  const int pb0 = (ty * 8) ^ sb, pb1 = (ty * 8 + 4) ^ sb;
  for (int kc = 0; kc < HID; kc += 32) {
#pragma unroll
    for (int u = 0; u < 4; u++) {
      int lin = tid + u * 256;
      int il = lin >> 3, kq = (lin & 7) * 4;
      int pi = il ^ (4 * ((il >> 5) & 1));
      const float* asrc;
      if (GATHER) {
        int row = i0 + il;
        int tok = xtok[(row & 63) * SEQL + (row >> 6)];  // x[b][t], row = t*64+b
        asrc = emb + (size_t)tok * HID + kc + kq;
      } else {
        asrc = A + (size_t)(i0 + il) * HID + kc + kq;
      }
      v4f av = *(const v4f*)asrc;
      v4f bv = *(const v4f*)(W + (size_t)(j0 + il) * HID + kc + kq);
      As[(kq + 0) * 132 + pi] = av[0]; As[(kq + 1) * 132 + pi] = av[1];
      As[(kq + 2) * 132 + pi] = av[2]; As[(kq + 3) * 132 + pi] = av[3];
      Bs[(kq + 0) * 132 + pi] = bv[0]; Bs[(kq + 1) * 132 + pi] = bv[1];
      Bs[(kq + 2) * 132 + pi] = bv[2]; Bs[(kq + 3) * 132 + pi] = bv[3];
    }
    __syncthreads();
#pragma unroll 8
    for (int k = 0; k < 32; k++) {
      v4f a0 = *(const v4f*)&As[k * 132 + pa0];
      v4f a1 = *(const v4f*)&As[k * 132 + pa1];
      v4f b0 = *(const v4f*)&Bs[k * 132 + pb0];
      v4f b1 = *(const v4f*)&Bs[k * 132 + pb1];
      float ar[8] = {a0[0], a0[1], a0[2], a0[3], a1[0], a1[1], a1[2], a1[3]};
      float br[8] = {b0[0], b0[1], b0[2], b0[3], b1[0], b1[1], b1[2], b1[3]};
#pragma unroll
      for (int r = 0; r < 8; r++)
#pragma unroll
        for (int c = 0; c < 8; c++) acc[r][c] = fmaf(ar[r], br[c], acc[r][c]);
    }
    __syncthreads();
  }
  v4f bl0 = *(const v4f*)(bias + j0 + ty * 8);
  v4f bl1 = *(const v4f*)(bias + j0 + ty * 8 + 4);
#pragma unroll
  for (int r = 0; r < 8; r++) {
    float* dst = P + (size_t)(i0 + tx * 8 + r) * HID + j0 + ty * 8;
    v4f o0 = {acc[r][0] + bl0[0], acc[r][1] + bl0[1], acc[r][2] + bl0[2], acc[r][3] + bl0[3]};
    v4f o1 = {acc[r][4] + bl1[0], acc[r][5] + bl1[1], acc[r][6] + bl1[2], acc[r][7] + bl1[3]};
    *(v4f*)dst = o0;
    *(v4f*)(dst + 4) = o1;
  }
}

// ---------------- R6/R7: pipelined 2-layer recurrence scan, flat sync ----------------
// 512 wgs. wgs 0-255: layer0 (8 bgroups x 32 jgroups, Whh0 slice in VGPRs), h0 into
// 4-slot ring. wgs 256-511: layer1 (Whh1+Wih1 slices in VGPRs), lag-1 behind layer0.
// Flags: arrivals only, flags[wgid]. No release lines (R7).
__global__ __launch_bounds__(256, 2) void k_scan2(
    const float* __restrict__ P0, const float* __restrict__ Wih,
    const float* __restrict__ Whh, const float* __restrict__ bih,
    const float* __restrict__ bhh, float* __restrict__ h0ring,
    float* __restrict__ h0buf, float* __restrict__ h1buf, int* __restrict__ flags) {
  __shared__ __align__(16) float hs0[32 * 132];
  __shared__ __align__(16) float hs1[32 * 132];
  const int wgid = blockIdx.x, tid = threadIdx.x;
  const int layer = wgid >> 8;
  const int wg = wgid & 255;
  const int bg = wg >> 5, jg = wg & 31;
  const int b0 = bg * 8, j0 = jg * 16;
  const int bh = tid & 1, jg2 = (tid >> 1) & 3, ks = tid >> 3;
  int* arr = &flags[wgid * FPAD];

  if (layer == 0) {
    v4f wv[4][4];
#pragma unroll
    for (int jj = 0; jj < 4; jj++)
#pragma unroll
      for (int i4 = 0; i4 < 4; i4++)
        wv[jj][i4] = *(const v4f*)(Whh + (size_t)(j0 + jg2 * 4 + jj) * HID + ks * 16 + i4 * 4);
    for (int t = 0; t < SEQL; t++) {
      // prefetch this wg's P0[t] slice (independent of staging -> overlaps compute)
      float pf = 0.f;
      if (tid < 128)
        pf = P0[(size_t)t * BH + (b0 + (tid >> 4)) * HID + j0 + (tid & 15)];
      const float* hsrc = h0ring + ((t + 3) & 3) * BH + b0 * HID;  // h0[t-1]; slot3 zeroed
#pragma unroll
      for (int u = 0; u < 16; u++) {
        int lin = tid + u * 256;
        int b = lin >> 9, k = lin & 511;
        hs0[(k >> 4) * 132 + b * 16 + (k & 15)] = ldf(hsrc + b * HID + k);
      }
      __syncthreads();
      float acc[4][4] = {};
#pragma unroll
      for (int i4 = 0; i4 < 4; i4++) {
#pragma unroll
        for (int bb = 0; bb < 4; bb++) {
          int b = bh * 4 + bb;
          v4f hv = *(const v4f*)&hs0[ks * 132 + b * 16 + i4 * 4];
#pragma unroll
          for (int jj = 0; jj < 4; jj++) {
            float a = acc[bb][jj];
            a = fmaf(hv[0], wv[jj][i4][0], a);
            a = fmaf(hv[1], wv[jj][i4][1], a);
            a = fmaf(hv[2], wv[jj][i4][2], a);
            a = fmaf(hv[3], wv[jj][i4][3], a);
            acc[bb][jj] = a;
          }
        }
      }
      __syncthreads();  // reuse hs0 as partials [ks32][b8][j16]
#pragma unroll
      for (int bb = 0; bb < 4; bb++) {
        v4f pv = {acc[bb][0], acc[bb][1], acc[bb][2], acc[bb][3]};
        *(v4f*)&hs0[ks * 132 + (bh * 4 + bb) * 16 + jg2 * 4] = pv;
      }
      __syncthreads();
      if (tid < 128) {
        int bb = tid >> 4, jj = tid & 15;
        float sum = 0.f;
#pragma unroll
        for (int k2 = 0; k2 < 32; k2++) sum += hs0[k2 * 132 + bb * 16 + jj];
        int jglob = j0 + jj, bglob = b0 + bb;
        float z = pf + bhh[jglob] + sum;
        float h = tanhf(z);
        stf(&h0ring[(t & 3) * BH + bglob * HID + jglob], h);
        if (t == SEQL - 1) stf(&h0buf[bglob * HID + jglob], h);  // decoder h0 seed (slot 0)
      }
      // R7 flat barrier: arrive, then poll own-bg L0 arrivals directly;
      // tid 32..63 poll L1 arrivals >= ep-3 (ring backpressure).
      unsigned ep = (unsigned)(t + 1);
      __atomic_signal_fence(__ATOMIC_SEQ_CST);
      __builtin_amdgcn_s_waitcnt(0);
      __syncthreads();
      if (tid == 0) stflag(arr, (int)ep);
      if (tid < 32) {
        while ((unsigned)ldflag(&flags[(bg * 32 + tid) * FPAD]) < ep)
          __builtin_amdgcn_s_sleep(1);
      } else if (tid < 64 && ep > 3) {
        while ((unsigned)ldflag(&flags[(256 + bg * 32 + (tid - 32)) * FPAD]) < ep - 3)
          __builtin_amdgcn_s_sleep(1);
      }
      __atomic_signal_fence(__ATOMIC_SEQ_CST);
      __syncthreads();
    }
  } else {
    v4f wvh[4][4], wvi[4][4];
#pragma unroll
    for (int jj = 0; jj < 4; jj++)
#pragma unroll
      for (int i4 = 0; i4 < 4; i4++) {
        size_t off = (size_t)(j0 + jg2 * 4 + jj) * HID + ks * 16 + i4 * 4;
        wvh[jj][i4] = *(const v4f*)(Whh + 262144 + off);
        wvi[jj][i4] = *(const v4f*)(Wih + 262144 + off);
      }
    for (int t = 0; t < SEQL; t++) {
      const int p1 = t & 1;
      // stage h1[t-1] (own-group data from previous barrier; slot 0 zeroed at t=0)
      const float* h1src = h1buf + p1 * BH + b0 * HID;
#pragma unroll
      for (int u = 0; u < 16; u++) {
        int lin = tid + u * 256;
        int b = lin >> 9, k = lin & 511;
        hs1[(k >> 4) * 132 + b * 16 + (k & 15)] = ldf(h1src + b * HID + k);
      }
      __syncthreads();
      float acc[4][4] = {};
#pragma unroll
      for (int i4 = 0; i4 < 4; i4++) {  // hh1 part overlaps the wait for h0[t]
#pragma unroll
        for (int bb = 0; bb < 4; bb++) {
          int b = bh * 4 + bb;
          v4f hv = *(const v4f*)&hs1[ks * 132 + b * 16 + i4 * 4];
#pragma unroll
          for (int jj = 0; jj < 4; jj++) {
            float a = acc[bb][jj];
            a = fmaf(hv[0], wvh[jj][i4][0], a);
            a = fmaf(hv[1], wvh[jj][i4][1], a);
            a = fmaf(hv[2], wvh[jj][i4][2], a);
            a = fmaf(hv[3], wvh[jj][i4][3], a);
            acc[bb][jj] = a;
          }
        }
      }
      // R7: wait for layer0's h0[t] by polling the 32 L0 arrival flags directly
      if (tid < 32) {
        while ((unsigned)ldflag(&flags[(bg * 32 + tid) * FPAD]) < (unsigned)(t + 1))
          __builtin_amdgcn_s_sleep(1);
      }
      __atomic_signal_fence(__ATOMIC_SEQ_CST);
      __syncthreads();
      const float* h0src = h0ring + (t & 3) * BH + b0 * HID;
#pragma unroll
      for (int u = 0; u < 16; u++) {
        int lin = tid + u * 256;
        int b = lin >> 9, k = lin & 511;
        hs0[(k >> 4) * 132 + b * 16 + (k & 15)] = ldf(h0src + b * HID + k);
      }
      __syncthreads();
#pragma unroll
      for (int i4 = 0; i4 < 4; i4++) {  // ih1 part
#pragma unroll
        for (int bb = 0; bb < 4; bb++) {
          int b = bh * 4 + bb;
          v4f hv = *(const v4f*)&hs0[ks * 132 + b * 16 + i4 * 4];
#pragma unroll
          for (int jj = 0; jj < 4; jj++) {
            float a = acc[bb][jj];
            a = fmaf(hv[0], wvi[jj][i4][0], a);
            a = fmaf(hv[1], wvi[jj][i4][1], a);
            a = fmaf(hv[2], wvi[jj][i4][2], a);
            a = fmaf(hv[3], wvi[jj][i4][3], a);
            acc[bb][jj] = a;
          }
        }
      }
      __syncthreads();  // reuse hs1 as partials
#pragma unroll
      for (int bb = 0; bb < 4; bb++) {
        v4f pv = {acc[bb][0], acc[bb][1], acc[bb][2], acc[bb][3]};
        *(v4f*)&hs1[ks * 132 + (bh * 4 + bb) * 16 + jg2 * 4] = pv;
      }
      __syncthreads();
      if (tid < 128) {
        int bb = tid >> 4, jj = tid & 15;
        float sum = 0.f;
#pragma unroll
        for (int k2 = 0; k2 < 32; k2++) sum += hs1[k2 * 132 + bb * 16 + jj];
        int jglob = j0 + jj, bglob = b0 + bb;
        float z = bih[HID + jglob] + bhh[HID + jglob] + sum;
        float h = tanhf(z);
        stf(&h1buf[(p1 ^ 1) * BH + bglob * HID + jglob], h);  // t=255 -> slot 0 (decoder seed)
      }
      // R7 flat own-bg barrier
      unsigned ep = (unsigned)(t + 1);
      __atomic_signal_fence(__ATOMIC_SEQ_CST);
      __builtin_amdgcn_s_waitcnt(0);
      __syncthreads();
      if (tid == 0) stflag(arr, (int)ep);
      if (tid < 32) {
        while ((unsigned)ldflag(&flags[(256 + bg * 32 + tid) * FPAD]) < ep)
          __builtin_amdgcn_s_sleep(1);
      }
      __atomic_signal_fence(__ATOMIC_SEQ_CST);
      __syncthreads();
    }
  }
}

// issue one 32KB Wfcb k-tile (128 cols x 128 k, bf16) into LDS via global_load_lds.
__device__ __forceinline__ void issue_tile(const unsigned short* __restrict__ Wfcb,
                                           float* buf, int wg, int tid, int T) {
  const int wv = tid >> 6, ln = tid & 63;
  const unsigned short* sb =
      Wfcb + (size_t)(wg * 128 + wv * 32 + (ln & 15)) * HID + T * 128 + (ln >> 4) * 8;
#pragma unroll
  for (int kc = 0; kc < 4; kc++)
#pragma unroll
    for (int fq = 0; fq < 2; fq++)
      __builtin_amdgcn_global_load_lds(
          (const unsigned int*)(sb + (size_t)fq * 16 * HID + kc * 32),
          (unsigned int*)(buf + wv * 2048 + kc * 512 + fq * 256), 16, 0, 0);
}

// ---------------- decoder phase kernels (R5: one dispatch per phase) ----------------
template <int PH>
__global__ __launch_bounds__(256, 1) void k_cell(
    const float* __restrict__ emb, const float* __restrict__ Wih,
    const float* __restrict__ Whh, const float* __restrict__ bih,
    const float* __restrict__ bhh, const u64* __restrict__ best,
    float* __restrict__ h0buf, float* __restrict__ h1buf,
    unsigned short* __restrict__ h1bf, int st) {
  __shared__ __align__(16) float Wl[2 * 4224];   // [ih,hh][ks32][j8][k16]+pad
  __shared__ __align__(16) float es[32 * 268];   // input stage / partials
  __shared__ __align__(16) float hss[32 * 268];  // h stage
  const int wg = blockIdx.x, tid = threadIdx.x;
  const int bg = wg >> 6, jgD = wg & 63;
  const int bh = tid & 3, jg2 = (tid >> 2) & 1, ks = tid >> 3;
  const int p = st & 1;
#pragma unroll
  for (int m = 0; m < 2; m++) {
    const float* src = (m ? Whh : Wih) + (size_t)PH * HID * HID;
#pragma unroll
    for (int u = 0; u < 4; u++) {
      int lin = tid + u * 256;
      int j = lin >> 7, k4 = (lin & 127) * 4;
      v4f v = *(const v4f*)(src + (size_t)(jgD * 8 + j) * HID + k4);
      *(v4f*)&Wl[m * 4224 + (k4 >> 4) * 132 + j * 16 + (k4 & 15)] = v;
    }
  }
  if (PH == 0) {
#pragma unroll
    for (int u = 0; u < 8; u++) {
      int lin = tid + u * 256;
      int b = lin >> 7, k4 = (lin & 127) * 4;
      unsigned vtok = 0u;
      if (st > 0) {
        u64 kk = best[bg * 16 + b];
        vtok = 0xFFFFFFFFu - (unsigned)(kk & 0xFFFFFFFFull);
        if (vtok >= (unsigned)NV) vtok = 0u;
      }
      v4f av = *(const v4f*)(emb + (size_t)vtok * HID + k4);
      *(v4f*)&es[(k4 >> 4) * 268 + b * 16 + (k4 & 15)] = av;
    }
#pragma unroll
    for (int u = 0; u < 32; u++) {
      int lin = tid + u * 256;
      int b = lin >> 9, k = lin & 511;
      hss[(k >> 4) * 268 + b * 16 + (k & 15)] = h0buf[p * BH + (bg * 16 + b) * HID + k];
    }
  } else {
#pragma unroll
    for (int u = 0; u < 32; u++) {
      int lin = tid + u * 256;
      int b = lin >> 9, k = lin & 511;
      int off = (k >> 4) * 268 + b * 16 + (k & 15);
      int row = (bg * 16 + b) * HID + k;
      es[off] = h0buf[(p ^ 1) * BH + row];
      hss[off] = h1buf[p * BH + row];
    }
  }
  __syncthreads();
  float acc[4][4] = {};
  const float* Wi = &Wl[0];
  const float* Wh = &Wl[4224];
#pragma unroll
  for (int i4 = 0; i4 < 4; i4++) {
    v4f wi[4], wh[4];
#pragma unroll
    for (int jj = 0; jj < 4; jj++) {
      wi[jj] = *(const v4f*)&Wi[ks * 132 + (jg2 * 4 + jj) * 16 + i4 * 4];
      wh[jj] = *(const v4f*)&Wh[ks * 132 + (jg2 * 4 + jj) * 16 + i4 * 4];
    }
#pragma unroll
    for (int bb = 0; bb < 4; bb++) {
      int b = bh * 4 + bb;
      v4f evv = *(const v4f*)&es[ks * 268 + b * 16 + i4 * 4];
      v4f hvv = *(const v4f*)&hss[ks * 268 + b * 16 + i4 * 4];
#pragma unroll
      for (int jj = 0; jj < 4; jj++) {
        float a = acc[bb][jj];
        a = fmaf(evv[0], wi[jj][0], a); a = fmaf(evv[1], wi[jj][1], a);
        a = fmaf(evv[2], wi[jj][2], a); a = fmaf(evv[3], wi[jj][3], a);
        a = fmaf(hvv[0], wh[jj][0], a); a = fmaf(hvv[1], wh[jj][1], a);
        a = fmaf(hvv[2], wh[jj][2], a); a = fmaf(hvv[3], wh[jj][3], a);
        acc[bb][jj] = a;
      }
    }
  }
  __syncthreads();  // partials alias es: [ks32][b16][j8]
#pragma unroll
  for (int bb = 0; bb < 4; bb++) {
    v4f pv = {acc[bb][0], acc[bb][1], acc[bb][2], acc[bb][3]};
    *(v4f*)&es[ks * 132 + (bh * 4 + bb) * 8 + jg2 * 4] = pv;
  }
  __syncthreads();
  if (tid < 128) {
    int b = tid >> 3, j = tid & 7;
    float sum = 0.f;
#pragma unroll
    for (int k2 = 0; k2 < 32; k2++) sum += es[k2 * 132 + b * 8 + j];
    int jglob = jgD * 8 + j, bglob = bg * 16 + b;
    float z = bih[PH * HID + jglob] + bhh[PH * HID + jglob] + sum;
    float h = tanhf(z);
    float* hb = (PH ? h1buf : h0buf);
    hb[(p ^ 1) * BH + bglob * HID + jglob] = h;
    if (PH) {  // pack bf16 pairs, even-j lanes store 4B
      unsigned hbv = f2bf(h);
      unsigned nb = (unsigned)__shfl_down((int)hbv, 1);
      if ((j & 1) == 0)
        *(unsigned*)(h1bf + (size_t)bglob * HID + jglob) = hbv | (nb << 16);
    }
  }
}

// logits = h1 @ Wfc^T + bfc (bf16 MFMA, Wfcb via LDS double-buffer) + per-wg col max.
__global__ __launch_bounds__(256, 1) void k_logits(
    const unsigned short* __restrict__ Wfcb, const unsigned short* __restrict__ h1bf,
    const float* __restrict__ bfc, float* __restrict__ out, float* __restrict__ pmaxp,
    u64* __restrict__ best, int st) {
  __shared__ __align__(16) float tb0[8192];
  __shared__ __align__(16) float tb1[8192];
  __shared__ float pmr[256];
  const int wg = blockIdx.x, tid = threadIdx.x;
  if (wg == 250) {
    if (tid < 64) best[tid] = 0ull;
    return;
  }
  const int w = tid >> 6, lane = tid & 63;
  const int l16 = lane & 15, quad = lane >> 4;
  const int n0 = wg * 128 + w * 32;
  const int nc0 = n0 + l16, nc1 = n0 + 16 + l16;
  const float bf0 = bfc[nc0], bf1 = bfc[nc1];
  issue_tile(Wfcb, tb0, wg, tid, 0);
  v4f acc[4][2] = {};
#pragma unroll
  for (int t = 0; t < 4; t++) {
    __builtin_amdgcn_sched_barrier(0);
    const float* buf = (t & 1) ? tb1 : tb0;
    union { u64 q[2]; short8 s; } au[4][4];
#pragma unroll
    for (int mb = 0; mb < 4; mb++) {
      const unsigned short* hr = h1bf + (size_t)(mb * 16 + l16) * HID + t * 128 + quad * 8;
#pragma unroll
      for (int kc = 0; kc < 4; kc++) {
        au[mb][kc].q[0] = *(const u64*)(hr + kc * 32);
        au[mb][kc].q[1] = *(const u64*)(hr + kc * 32 + 4);
      }
    }
    __builtin_amdgcn_sched_barrier(0);
    if (t < 3) issue_tile(Wfcb, (t & 1) ? tb0 : tb1, wg, tid, t + 1);
    __builtin_amdgcn_sched_barrier(0);
    if (t < 3) asm volatile("s_waitcnt vmcnt(8)" ::: "memory");
    else       asm volatile("s_waitcnt vmcnt(0)" ::: "memory");
    __builtin_amdgcn_sched_barrier(0);
#pragma unroll
    for (int kc = 0; kc < 4; kc++) {
      short8 b0 = *(const short8*)(buf + w * 2048 + kc * 512 + lane * 4);
      short8 b1 = *(const short8*)(buf + w * 2048 + kc * 512 + 256 + lane * 4);
#pragma unroll
      for (int mb = 0; mb < 4; mb++) {
        acc[mb][0] =
            __builtin_amdgcn_mfma_f32_16x16x32_bf16(au[mb][kc].s, b0, acc[mb][0], 0, 0, 0);
        acc[mb][1] =
            __builtin_amdgcn_mfma_f32_16x16x32_bf16(au[mb][kc].s, b1, acc[mb][1], 0, 0, 0);
      }
    }
  }
#pragma unroll
  for (int mb = 0; mb < 4; mb++) {
#pragma unroll
    for (int r = 0; r < 4; r++) {
      float v0 = acc[mb][0][r] + bf0;
      float v1 = acc[mb][1][r] + bf1;
      int m = mb * 16 + quad * 4 + r;  // C/D: col=lane&15, row=quad*4+reg
      out[(size_t)(m * TDEC + st) * NV + nc0] = v0;
      out[(size_t)(m * TDEC + st) * NV + nc1] = v1;
      float mx = fmaxf(v0, v1);
      mx = fmaxf(mx, __shfl_xor(mx, 1));
      mx = fmaxf(mx, __shfl_xor(mx, 2));
      mx = fmaxf(mx, __shfl_xor(mx, 4));
      mx = fmaxf(mx, __shfl_xor(mx, 8));
      if (l16 == 0) pmr[w * 64 + m] = mx;
    }
  }
  __syncthreads();
  if (tid < 64) {
    float m4 = fmaxf(fmaxf(pmr[tid], pmr[64 + tid]), fmaxf(pmr[128 + tid], pmr[192 + tid]));
    pmaxp[tid * 256 + wg] = m4;  // b-major: argmax reads 250 contiguous floats
  }
}

// candidate refine + argmax. grid 256: wg = b*4 + quarter (8000 vocab each).
__global__ __launch_bounds__(256, 1) void k_argmax(
    const float* __restrict__ Wfc, const float* __restrict__ bfc,
    const float* __restrict__ h1buf, const float* __restrict__ pmaxp,
    const float* __restrict__ out, u64* __restrict__ best, int st) {
  __shared__ __align__(16) float hcache[512];
  __shared__ float red[256];
  const int wg = blockIdx.x, tid = threadIdx.x;
  const int b = wg >> 2, q = wg & 3;
  const int p = st & 1;
  const float* hrow = h1buf + (p ^ 1) * BH + b * HID;
  hcache[tid] = hrow[tid];
  hcache[tid + 256] = hrow[tid + 256];
  red[tid] = (tid < 250) ? pmaxp[b * 256 + tid] : -3.0e38f;
  __syncthreads();
  for (int o = 128; o > 0; o >>= 1) {
    if (tid < o) red[tid] = fmaxf(red[tid], red[tid + o]);
    __syncthreads();
  }
  const float thr = red[0] - 0.05f;
  const size_t ob = (size_t)(b * TDEC + st) * NV + q * 8000;
  for (int i = tid * 2; i < 8000; i += 512) {
    u64 qq = *(const u64*)(out + ob + i);
    float lv[2] = {__uint_as_float((unsigned)qq), __uint_as_float((unsigned)(qq >> 32))};
#pragma unroll
    for (int c = 0; c < 2; c++) {
      if (lv[c] >= thr) {
        int vidx = q * 8000 + i + c;
        const v4f* h4 = (const v4f*)hcache;
        const v4f* w4 = (const v4f*)(Wfc + (size_t)vidx * HID);
        v4f s0 = 0, s1 = 0;
        for (int k = 0; k < 128; k += 2) {
          s0 += h4[k] * w4[k];
          s1 += h4[k + 1] * w4[k + 1];
        }
        v4f sv = s0 + s1;
        float d = bfc[vidx] + sv[0] + sv[1] + sv[2] + sv[3];
        u64 key = ((u64)fenc(d) << 32) | (u64)(0xFFFFFFFFu - (unsigned)vidx);
        atomicMax(&best[b], key);
      }
    }
  }
}

// h_fin epilogue: [2][64][512] appended after logits (final h lives in slot 0)
__global__ void k_hfin(const float* __restrict__ h0buf, const float* __restrict__ h1buf,
                       float* __restrict__ out) {
  int lin = (int)blockIdx.x * 256 + (int)threadIdx.x;
  int l = lin >> 15, r2 = lin & 32767;
  out[65536000 + lin] = (l ? h1buf : h0buf)[r2];
}

extern "C" void kernel_launch(void* const* d_in, const int* in_sizes, int n_in, void* d_out,
                              int out_size, void* d_ws, size_t ws_size, hipStream_t stream) {
  const int* x = (const int*)d_in[0];
  const float* emb = (const float*)d_in[1];
  const float* Wih = (const float*)d_in[2];
  const float* Whh = (const float*)d_in[3];
  const float* bih = (const float*)d_in[4];
  const float* bhh = (const float*)d_in[5];
  const float* Wfc = (const float*)d_in[6];
  const float* bfc = (const float*)d_in[7];
  float* out = (float*)d_out;
  char* ws = (char*)d_ws;

  float* P0 = (float*)ws;                          // [256][64][512]
  float* P1space = P0 + (size_t)SEQL * BH;         // old P1 region; h0ring lives here
  float* h0ring = P1space;                         // [4][64][512] ring (R6)
  unsigned short* Wfcb = (unsigned short*)(P1space + (size_t)SEQL * BH);  // [32000][512] bf16
  char* small = (char*)(Wfcb + (size_t)NV * HID);
  float* h0buf = (float*)small;                    // [2][64][512] (decoder state)
  float* h1buf = h0buf + 2 * BH;                   // [2][64][512]
  unsigned short* h1bf = (unsigned short*)(h1buf + 2 * BH);  // [64][512] bf16
  float* pmaxp = (float*)(h1bf + BH);              // [64 b][256 wg] (b-major)
  u64* best = (u64*)(pmaxp + 256 * 64);            // [64]
  int* flags = (int*)(best + 64);                  // [512 arrivals * FPAD]
  size_t small_bytes = (size_t)2 * BH * 4 + (size_t)2 * BH * 4 + BH * 2 + 256 * 64 * 4 +
                       64 * 8 + (512 + 16) * FPAD * 4;

  hipMemsetAsync(small, 0, small_bytes, stream);       // h=0, best=0, flags epoch 0
  hipMemsetAsync(h0ring, 0, (size_t)4 * BH * 4, stream);  // ring slot 3 = h0[-1] = 0
  k_wfcb<<<2048, 256, 0, stream>>>(Wfc, Wfcb);
  // encoder layer0 ih-part: P0 = gather(emb, x) @ Wih0^T + bih0
  k_gemm<1><<<512, 256, 0, stream>>>(nullptr, x, emb, Wih, bih, P0);
  // R6/R7: pipelined 2-layer scan, flat sync
  k_scan2<<<512, 256, 0, stream>>>(P0, Wih, Whh, bih, bhh, h0ring, h0buf, h1buf, flags);
  // decoder: 32 steps x 4 stream-ordered phase dispatches (R5)
  for (int st = 0; st < TDEC; st++) {
    k_cell<0><<<256, 256, 0, stream>>>(emb, Wih, Whh, bih, bhh, best, h0buf, h1buf, h1bf, st);
    k_cell<1><<<256, 256, 0, stream>>>(emb, Wih, Whh, bih, bhh, best, h0buf, h1buf, h1bf, st);
    k_logits<<<251, 256, 0, stream>>>(Wfcb, h1bf, bfc, out, pmaxp, best, st);
    k_argmax<<<256, 256, 0, stream>>>(Wfc, bfc, h1buf, pmaxp, out, best, st);
  }
  k_hfin<<<256, 256, 0, stream>>>(h0buf, h1buf, out);
}